// Round 2
// baseline (2242.777 us; speedup 1.0000x reference)
//
#include <hip/hip_runtime.h>
#include <stdint.h>

// All FP in this file must match XLA's HLO op-for-op: no mul+add contraction.
#pragma clang fp contract(off)

typedef unsigned long long u64;
typedef uint32_t u32;

// ====================================================================
// JAX PRNG variant. Modern JAX (>=0.4.36) defaults
// jax_threefry_partitionable=True  -> per-element counter (0, i), 32-bit
// draw = out0 ^ out1. Legacy scheme: counter halves (i, i+n/2) -> out0/out1.
// If bench fails with absmax O(1..100) -> selection mismatch -> flip to 0.
// ====================================================================
#define JAX_PARTITIONABLE 1

#define M_PROP 200000u
#define N_GT   128u
#define NM     25600000u
// keep negative-priority candidates with m >= 2^23 - 2^12 (expect ~12.4k
// of 25.5M; the true top-128 are inside with astronomical margin)
#define NEG_MCUT 8384512u
#define COMP_CAP 8192u

// ---------------- threefry2x32 (20 rounds) ----------------
__host__ __device__ inline void tf2x32(u32 k0, u32 k1, u32 x0, u32 x1,
                                       u32& o0, u32& o1) {
  u32 ks0 = k0, ks1 = k1, ks2 = k0 ^ k1 ^ 0x1BD11BDAu;
  x0 += ks0; x1 += ks1;
#define TF_R(r) { x0 += x1; x1 = (x1 << r) | (x1 >> (32 - r)); x1 ^= x0; }
  TF_R(13) TF_R(15) TF_R(26) TF_R(6)
  x0 += ks1; x1 += ks2 + 1u;
  TF_R(17) TF_R(29) TF_R(16) TF_R(24)
  x0 += ks2; x1 += ks0 + 2u;
  TF_R(13) TF_R(15) TF_R(26) TF_R(6)
  x0 += ks0; x1 += ks1 + 3u;
  TF_R(17) TF_R(29) TF_R(16) TF_R(24)
  x0 += ks1; x1 += ks2 + 4u;
  TF_R(13) TF_R(15) TF_R(26) TF_R(6)
  x0 += ks2; x1 += ks0 + 5u;
#undef TF_R
  o0 = x0; o1 = x1;
}

// 32 random bits for element idx of an n-element draw with key (ka,kb)
__device__ inline u32 jax_bits32(u32 ka, u32 kb, u32 idx, u32 n) {
#if JAX_PARTITIONABLE
  (void)n;
  u32 a, b; tf2x32(ka, kb, 0u, idx, a, b);
  return a ^ b;
#else
  u32 h = n >> 1;  // all our n are even
  u32 a, b;
  if (idx < h) { tf2x32(ka, kb, idx, idx + h, a, b); return a; }
  else         { tf2x32(ka, kb, idx - h, idx, a, b); return b; }
#endif
}

// k1,k2,k3 = jax.random.split(jax.random.key(42), 3)
static void jax_split3(u32& k1a, u32& k1b, u32& k2a, u32& k2b,
                       u32& k3a, u32& k3b) {
  const u32 K0 = 0u, K1 = 42u;
#if JAX_PARTITIONABLE
  tf2x32(K0, K1, 0u, 0u, k1a, k1b);
  tf2x32(K0, K1, 0u, 1u, k2a, k2b);
  tf2x32(K0, K1, 0u, 2u, k3a, k3b);
#else
  u32 y00, y10, y01, y11, y02, y12;
  tf2x32(K0, K1, 0u, 3u, y00, y10);
  tf2x32(K0, K1, 1u, 4u, y01, y11);
  tf2x32(K0, K1, 2u, 5u, y02, y12);
  // out = [y00,y01,y02,y10,y11,y12] reshaped (3,2)
  k1a = y00; k1b = y01;
  k2a = y02; k2b = y10;
  k3a = y11; k3b = y12;
#endif
}

// wave-aggregated buffer append (one atomic per wave per predicate)
__device__ inline u32 wave_append_slot(u32* ctr, bool pred, bool& any) {
  u64 mask = __ballot(pred);
  if (mask == 0ull) { any = false; return 0u; }
  any = true;
  u32 lane = threadIdx.x & 63u;
  u32 prefix = (u32)__popcll(mask & ((1ull << lane) - 1ull));
  int leader = __ffsll(mask) - 1;
  u32 base = 0u;
  if ((int)lane == leader) base = atomicAdd(ctr, (u32)__popcll(mask));
  base = __shfl(base, leader, 64);
  return base + prefix;
}

__global__ __launch_bounds__(64) void rpn_init(u32* counters) {
  if (threadIdx.x < 16u) counters[threadIdx.x] = 0u;
}

// ---------------- pass 1: IoU + candidate collection ----------------
__global__ __launch_bounds__(256) void rpn_collect(
    const float4* __restrict__ props, const float4* __restrict__ gt,
    uint4* __restrict__ posBuf, u32 posCap,
    u64* __restrict__ iou2Buf, u32 iou2Cap,
    u64* __restrict__ negBuf, u32 negCap,
    u32* __restrict__ counters,
    u32 k1a, u32 k1b, u32 k3a, u32 k3b) {
  __shared__ float4 gtS[N_GT];
  for (u32 j = threadIdx.x; j < N_GT; j += blockDim.x) gtS[j] = gt[j];
  __syncthreads();
  u32 p = blockIdx.x * blockDim.x + threadIdx.x;
  if (p >= M_PROP) return;  // M_PROP % 64 == 0 -> whole waves exit
  float4 pb = props[p];
  float pa = (pb.z - pb.x) * (pb.w - pb.y);
  for (u32 g = 0; g < N_GT; ++g) {
    float4 gb = gtS[g];
    float ga = (gb.z - gb.x) * (gb.w - gb.y);
    float wx = fminf(gb.z, pb.z) - fmaxf(gb.x, pb.x);
    float wy = fminf(gb.w, pb.w) - fmaxf(gb.y, pb.y);
    wx = fmaxf(wx, 0.0f); wy = fmaxf(wy, 0.0f);
    float inter = wx * wy;
    float iou = inter / (ga + pa - inter);
    u32 idx = g * M_PROP + p;

    bool isPos = iou > 0.4f;
    bool isI2 = (!isPos) && (iou > 0.25f);  // backup pool for best_idx top-128
    bool isNeg = false; u32 m3v = 0u;
    if (!isPos && !isI2 && (iou < 0.1f)) {
      m3v = jax_bits32(k3a, k3b, idx, NM) >> 9;
      isNeg = (m3v >= NEG_MCUT);
    }
    bool any; u32 s;
    s = wave_append_slot(&counters[0], isPos, any);
    if (any && isPos && s < posCap) {
      u32 m1 = jax_bits32(k1a, k1b, idx, NM) >> 9;
      posBuf[s] = make_uint4(idx, __float_as_uint(iou), m1, 0u);
    }
    s = wave_append_slot(&counters[2], isI2, any);
    if (any && isI2 && s < iou2Cap)
      iou2Buf[s] = ((u64)__float_as_uint(iou) << 25) | (u64)(0x1FFFFFFu - idx);
    s = wave_append_slot(&counters[1], isNeg, any);
    if (any && isNeg && s < negCap)
      negBuf[s] = ((u64)m3v << 25) | (u64)(0x1FFFFFFu - idx);
  }
}

// ---------------- pass 2: exact top-k selections + loss ----------------
__device__ inline u32 iouBin(u32 bits) {  // monotone bins over (0.25, 1.0]
  u32 b = (bits - 0x3E800000u) >> 14;
  return b > 1023u ? 1023u : b;
}

__device__ inline void wave_max64(u64& k, u32& i) {
  for (int off = 32; off > 0; off >>= 1) {
    u64 ok = __shfl_xor(k, off, 64);
    u32 oi = __shfl_xor(i, off, 64);
    if (ok > k) { k = ok; i = oi; }
  }
}

// extract 128 largest keys (desc); key==0 is the empty sentinel
__device__ inline void extract128(u64* keyBuf, u32 nc, u64* redK, u32* redI,
                                  u64* selKey, u32 lane, u32 wid) {
  const u32 tid = threadIdx.x;
  for (u32 r = 0u; r < 128u; ++r) {
    u64 bk = 0ull; u32 bi = 0xFFFFFFFFu;
    for (u32 i = tid; i < nc; i += blockDim.x) {
      u64 k = keyBuf[i];
      if (k > bk) { bk = k; bi = i; }
    }
    wave_max64(bk, bi);
    if (lane == 0u) { redK[wid] = bk; redI[wid] = bi; }
    __syncthreads();
    if (wid == 0u) {
      u64 k2 = (lane < 16u) ? redK[lane] : 0ull;
      u32 i2 = (lane < 16u) ? redI[lane] : 0xFFFFFFFFu;
      wave_max64(k2, i2);
      if (lane == 0u) {
        selKey[r] = k2;
        if (k2 != 0ull && i2 != 0xFFFFFFFFu) keyBuf[i2] = 0ull;
      }
    }
    __syncthreads();
  }
}

__device__ inline float sl1(float d) {
  float ad = fabsf(d);
  return (ad < 1.0f) ? 0.5f * d * d : ad - 0.5f;
}

__global__ __launch_bounds__(1024) void rpn_finalize(
    const float* __restrict__ obj, const float4* __restrict__ props,
    const float4* __restrict__ gt,
    const uint4* __restrict__ posBuf, u32 posCap,
    const u64* __restrict__ iou2Buf, u32 iou2Cap,
    const u64* __restrict__ negBuf, u32 negCap,
    const u32* __restrict__ counters, float* __restrict__ out,
    u32 k2a, u32 k2b) {
  __shared__ u32 hist[1024];
  __shared__ u64 keyBuf[COMP_CAP];
  __shared__ u64 redK[16];
  __shared__ u32 redI[16];
  __shared__ u64 selKey[128];
  __shared__ u32 bestIdx[128];
  __shared__ float fred[1024];
  __shared__ u32 s_cnt, s_cut;
  __shared__ float s_reg, s_bcep;

  const u32 tid = threadIdx.x;
  const u32 lane = tid & 63u;
  const u32 wid = tid >> 6;
  const u32 nPos = counters[0] < posCap ? counters[0] : posCap;
  const u32 nNeg = counters[1] < negCap ? counters[1] : negCap;
  const u32 nI2 = counters[2] < iou2Cap ? counters[2] : iou2Cap;

  // ===== Phase 1: best_idx = top-128 of flat IoU (desc, ties idx asc) =====
  for (u32 i = tid; i < 1024u; i += 1024u) hist[i] = 0u;
  __syncthreads();
  for (u32 i = tid; i < nPos; i += 1024u) atomicAdd(&hist[iouBin(posBuf[i].y)], 1u);
  for (u32 i = tid; i < nI2; i += 1024u) atomicAdd(&hist[iouBin((u32)(iou2Buf[i] >> 25))], 1u);
  __syncthreads();
  if (tid == 0u) {
    u32 cum = 0u, b = 1024u;
    while (b > 0u) { --b; cum += hist[b]; if (cum >= 128u) break; }
    s_cut = b; s_cnt = 0u;
  }
  __syncthreads();
  u32 cut = s_cut;
  for (u32 i = tid; i < nPos; i += 1024u) {
    uint4 r = posBuf[i];
    if (iouBin(r.y) >= cut) {
      u32 s = atomicAdd(&s_cnt, 1u);
      if (s < COMP_CAP) keyBuf[s] = ((u64)r.y << 25) | (u64)(0x1FFFFFFu - r.x);
    }
  }
  for (u32 i = tid; i < nI2; i += 1024u) {
    u64 k = iou2Buf[i];
    if (iouBin((u32)(k >> 25)) >= cut) {
      u32 s = atomicAdd(&s_cnt, 1u);
      if (s < COMP_CAP) keyBuf[s] = k;
    }
  }
  __syncthreads();
  u32 nc = s_cnt < COMP_CAP ? s_cnt : COMP_CAP;
  extract128(keyBuf, nc, redK, redI, selKey, lane, wid);
  if (tid < 128u) {
    u64 k = selKey[tid];
    bestIdx[tid] = (k == 0ull) ? 0u : (0x1FFFFFFu - (u32)(k & 0x1FFFFFFu));
  }
  __syncthreads();

  // ===== Phase 2: positives = top-128 of [best_prio(128) ++ pos_prio] =====
  for (u32 i = tid; i < 1024u; i += 1024u) hist[i] = 0u;
  __syncthreads();
  u32 myExtraM = 0u;
  if (tid < 128u) {
    myExtraM = jax_bits32(k2a, k2b, tid, 128u) >> 9;
    atomicAdd(&hist[myExtraM >> 13], 1u);
  }
  for (u32 i = tid; i < nPos; i += 1024u) atomicAdd(&hist[posBuf[i].z >> 13], 1u);
  __syncthreads();
  if (tid == 0u) {
    u32 cum = 0u, b = 1024u;
    while (b > 0u) { --b; cum += hist[b]; if (cum >= 128u) break; }
    s_cut = b; s_cnt = 0u;
  }
  __syncthreads();
  cut = s_cut;
  if (tid < 128u && (myExtraM >> 13) >= cut) {
    u32 s = atomicAdd(&s_cnt, 1u);
    if (s < COMP_CAP) keyBuf[s] = ((u64)myExtraM << 25) | (u64)(0x1FFFFFFu - tid);
  }
  for (u32 i = tid; i < nPos; i += 1024u) {
    uint4 r = posBuf[i];
    if ((r.z >> 13) >= cut) {
      u32 s = atomicAdd(&s_cnt, 1u);
      if (s < COMP_CAP) keyBuf[s] = ((u64)r.z << 25) | (u64)(0x1FFFFFFu - (r.x + 128u));
    }
  }
  __syncthreads();
  nc = s_cnt < COMP_CAP ? s_cnt : COMP_CAP;
  extract128(keyBuf, nc, redK, redI, selKey, lane, wid);

  float locReg = 0.0f, locBce = 0.0f;
  if (tid < 128u) {
    u64 k = selKey[tid];
    if (k != 0ull) {
      u32 c = 0x1FFFFFFu - (u32)(k & 0x1FFFFFFu);
      u32 pair = (c < 128u) ? bestIdx[c] : (c - 128u);
      if (pair < NM) {
        u32 row = pair / M_PROP, col = pair % M_PROP;
        float4 pr = props[col];
        float4 gb = gt[row];
        locReg = sl1(pr.x - gb.x) + sl1(pr.y - gb.y) +
                 sl1(pr.z - gb.z) + sl1(pr.w - gb.w);
        float l = obj[col];
        locBce = fmaxf(l, 0.0f) - l + log1pf(expf(-fabsf(l)));
      }
    }
  }
  fred[tid] = locReg; __syncthreads();
  for (u32 off = 512u; off > 0u; off >>= 1) { if (tid < off) fred[tid] += fred[tid + off]; __syncthreads(); }
  if (tid == 0u) s_reg = fred[0];
  __syncthreads();
  fred[tid] = locBce; __syncthreads();
  for (u32 off = 512u; off > 0u; off >>= 1) { if (tid < off) fred[tid] += fred[tid + off]; __syncthreads(); }
  if (tid == 0u) s_bcep = fred[0];
  __syncthreads();

  // ===== Phase 3: negatives = top-128 of neg_prio =====
  for (u32 i = tid; i < 1024u; i += 1024u) hist[i] = 0u;
  __syncthreads();
  for (u32 i = tid; i < nNeg; i += 1024u) {
    u32 m = (u32)(negBuf[i] >> 25);
    atomicAdd(&hist[(m & 0xFFFu) >> 2], 1u);  // m in [2^23-2^12, 2^23)
  }
  __syncthreads();
  if (tid == 0u) {
    u32 cum = 0u, b = 1024u;
    while (b > 0u) { --b; cum += hist[b]; if (cum >= 128u) break; }
    s_cut = b; s_cnt = 0u;
  }
  __syncthreads();
  cut = s_cut;
  for (u32 i = tid; i < nNeg; i += 1024u) {
    u64 k = negBuf[i];
    u32 m = (u32)(k >> 25);
    if (((m & 0xFFFu) >> 2) >= cut) {
      u32 s = atomicAdd(&s_cnt, 1u);
      if (s < COMP_CAP) keyBuf[s] = k;
    }
  }
  __syncthreads();
  nc = s_cnt < COMP_CAP ? s_cnt : COMP_CAP;
  extract128(keyBuf, nc, redK, redI, selKey, lane, wid);

  float locBceN = 0.0f;
  if (tid < 128u) {
    u64 k = selKey[tid];
    if (k != 0ull) {
      u32 idx = 0x1FFFFFFu - (u32)(k & 0x1FFFFFFu);
      u32 col = idx % M_PROP;
      float l = obj[col];
      locBceN = fmaxf(l, 0.0f) + log1pf(expf(-fabsf(l)));
    }
  }
  fred[tid] = locBceN; __syncthreads();
  for (u32 off = 512u; off > 0u; off >>= 1) { if (tid < off) fred[tid] += fred[tid + off]; __syncthreads(); }
  if (tid == 0u) {
    float cls = (s_bcep + fred[0]) / 256.0f;
    float reg = s_reg / 512.0f;
    out[0] = cls + 10.0f * reg;
  }
}

extern "C" void kernel_launch(void* const* d_in, const int* in_sizes, int n_in,
                              void* d_out, int out_size, void* d_ws, size_t ws_size,
                              hipStream_t stream) {
  (void)in_sizes; (void)n_in; (void)out_size;
  const float* obj = (const float*)d_in[0];
  const float4* props = (const float4*)d_in[1];
  const float4* gt = (const float4*)d_in[2];
  float* out = (float*)d_out;

  u32 k1a, k1b, k2a, k2b, k3a, k3b;
  jax_split3(k1a, k1b, k2a, k2b, k3a, k3b);

  size_t posCap = 2000000, iou2Cap = 524288, negCap = 262144;
  size_t avail = ws_size > 256 ? ws_size - 256 : 0;
  size_t need = posCap * 16 + iou2Cap * 8 + negCap * 8;
  if (avail < need && need > 0) {
    double f = (double)avail / (double)need;
    posCap = (size_t)(posCap * f);
    iou2Cap = (size_t)(iou2Cap * f);
    negCap = (size_t)(negCap * f);
  }
  uint8_t* base = (uint8_t*)d_ws;
  u32* counters = (u32*)base;
  uint4* posBuf = (uint4*)(base + 256);
  u64* iou2Buf = (u64*)(base + 256 + posCap * 16);
  u64* negBuf = (u64*)(base + 256 + posCap * 16 + iou2Cap * 8);

  rpn_init<<<1, 64, 0, stream>>>(counters);
  rpn_collect<<<(M_PROP + 255) / 256, 256, 0, stream>>>(
      props, gt, posBuf, (u32)posCap, iou2Buf, (u32)iou2Cap,
      negBuf, (u32)negCap, counters, k1a, k1b, k3a, k3b);
  rpn_finalize<<<1, 1024, 0, stream>>>(
      obj, props, gt, posBuf, (u32)posCap, iou2Buf, (u32)iou2Cap,
      negBuf, (u32)negCap, counters, out, k2a, k2b);
}

// Round 3
// 696.305 us; speedup vs baseline: 3.2210x; 3.2210x over previous
//
#include <hip/hip_runtime.h>
#include <stdint.h>

// All FP must match XLA's HLO op-for-op: no mul+add contraction.
#pragma clang fp contract(off)

typedef unsigned long long u64;
typedef uint32_t u32;

#define M_PROP 200000u
#define N_GT   128u
#define NM     25600000u

// priority cuts (23-bit priorities). Guarantees (all with >=40 sigma margin
// on binomial counts, validated by R2's measured candidate volumes):
//  B: pos pairs (iou>0.4, ~500k) with m1 >= 2^23-2^17 -> ~7.8k kept, and
//     #kept>=128 ==> top-128 pos keys all kept (exact).
//  C: neg pairs (iou<0.1, ~25.1M) with m3 >= 2^23-2^12 -> ~12.3k kept.
#define BCUT 8257536u   // 2^23 - 2^17
#define CCUT 8384512u   // 2^23 - 2^12

#define LA_CAP 3072u
#define LBC_CAP 512u
#define TOPA_CAP 8192u
#define COMP_CAP 8192u

// counters slots: 0=cntA 1=cntB 2=cntC 3=cntTopA 4=cutA
// ---------------- threefry2x32 (20 rounds) ----------------
__host__ __device__ inline void tf2x32(u32 k0, u32 k1, u32 x0, u32 x1,
                                       u32& o0, u32& o1) {
  u32 ks0 = k0, ks1 = k1, ks2 = k0 ^ k1 ^ 0x1BD11BDAu;
  x0 += ks0; x1 += ks1;
#define TF_R(r) { x0 += x1; x1 = (x1 << r) | (x1 >> (32 - r)); x1 ^= x0; }
  TF_R(13) TF_R(15) TF_R(26) TF_R(6)
  x0 += ks1; x1 += ks2 + 1u;
  TF_R(17) TF_R(29) TF_R(16) TF_R(24)
  x0 += ks2; x1 += ks0 + 2u;
  TF_R(13) TF_R(15) TF_R(26) TF_R(6)
  x0 += ks0; x1 += ks1 + 3u;
  TF_R(17) TF_R(29) TF_R(16) TF_R(24)
  x0 += ks1; x1 += ks2 + 4u;
  TF_R(13) TF_R(15) TF_R(26) TF_R(6)
  x0 += ks2; x1 += ks0 + 5u;
#undef TF_R
  o0 = x0; o1 = x1;
}

// partitionable threefry: 32 bits for element idx
__device__ inline u32 jax_bits32(u32 ka, u32 kb, u32 idx) {
  u32 a, b; tf2x32(ka, kb, 0u, idx, a, b);
  return a ^ b;
}

static void jax_split3(u32& k1a, u32& k1b, u32& k2a, u32& k2b,
                       u32& k3a, u32& k3b) {
  const u32 K0 = 0u, K1 = 42u;
  tf2x32(K0, K1, 0u, 0u, k1a, k1b);
  tf2x32(K0, K1, 0u, 1u, k2a, k2b);
  tf2x32(K0, K1, 0u, 2u, k3a, k3b);
}

// wave-aggregated append (one atomic per wave per predicate); works for LDS
// and global counters.
__device__ inline u32 wave_append_slot(u32* ctr, bool pred, bool& any) {
  u64 mask = __ballot(pred);
  if (mask == 0ull) { any = false; return 0u; }
  any = true;
  u32 lane = threadIdx.x & 63u;
  u32 prefix = (u32)__popcll(mask & ((1ull << lane) - 1ull));
  int leader = __ffsll(mask) - 1;
  u32 base = 0u;
  if ((int)lane == leader) base = atomicAdd(ctr, (u32)__popcll(mask));
  base = __shfl(base, leader, 64);
  return base + prefix;
}

__device__ inline u32 iouBin(u32 bits) {  // monotone bins over (0.25, 1.0]
  u32 b = (bits - 0x3E800000u) >> 14;
  return b > 1023u ? 1023u : b;
}

// ---------------- K0: zero counters + global histogram ----------------
__global__ __launch_bounds__(256) void rpn_init(u32* counters, u32* gHistA) {
  u32 tid = threadIdx.x;
  if (tid < 64u) counters[tid] = 0u;
  for (u32 i = tid; i < 1024u; i += 256u) gHistA[i] = 0u;
}

// ---------------- K1: IoU + filtered candidate collection ----------------
__global__ __launch_bounds__(256) void rpn_collect(
    const float4* __restrict__ props, const float4* __restrict__ gt,
    u64* __restrict__ bufA, u32 capA,
    u64* __restrict__ bufB, u32 capB,
    u64* __restrict__ bufC, u32 capC,
    u32* __restrict__ counters, u32* __restrict__ gHistA,
    u32 k1a, u32 k1b, u32 k3a, u32 k3b) {
  __shared__ float4 gtS[N_GT];
  __shared__ u64 lA[LA_CAP];
  __shared__ u64 lB[LBC_CAP];
  __shared__ u64 lC[LBC_CAP];
  __shared__ u32 hA[1024];
  __shared__ u32 cA, cB, cC, flushBase;

  const u32 tid = threadIdx.x;
  for (u32 i = tid; i < 1024u; i += 256u) hA[i] = 0u;
  for (u32 j = tid; j < N_GT; j += 256u) gtS[j] = gt[j];
  if (tid == 0u) { cA = 0u; cB = 0u; cC = 0u; }
  __syncthreads();

  u32 p = blockIdx.x * 256u + tid;
  bool active = p < M_PROP;
  float4 pb = make_float4(0.f, 0.f, 0.f, 0.f);
  if (active) pb = props[p];
  float pa = (pb.z - pb.x) * (pb.w - pb.y);

#define FLUSH(cX, lX, ctrIdx, bufX, capX)                                   \
  {                                                                          \
    if (tid == 0u) flushBase = atomicAdd(&counters[ctrIdx], cX);             \
    __syncthreads();                                                         \
    for (u32 i = tid; i < cX; i += 256u) {                                   \
      u32 d = flushBase + i;                                                 \
      if (d < capX) bufX[d] = lX[i];                                         \
    }                                                                        \
    __syncthreads();                                                         \
    if (tid == 0u) cX = 0u;                                                  \
    __syncthreads();                                                         \
  }

  for (u32 g = 0u; g < N_GT; ++g) {
    float4 gb = gtS[g];
    float ga = (gb.z - gb.x) * (gb.w - gb.y);
    float wx = fminf(gb.z, pb.z) - fmaxf(gb.x, pb.x);
    float wy = fminf(gb.w, pb.w) - fmaxf(gb.y, pb.y);
    wx = fmaxf(wx, 0.0f); wy = fmaxf(wy, 0.0f);
    float inter = wx * wy;
    float iou = inter / (ga + pa - inter);
    u32 idx = g * M_PROP + p;
    u32 ibits = __float_as_uint(iou);

    bool inA = active && (iou > 0.25f);
    bool any; u32 s;
    s = wave_append_slot(&cA, inA, any);
    if (inA) {
      lA[s] = ((u64)ibits << 25) | (u64)(0x1FFFFFFu - idx);
      atomicAdd(&hA[iouBin(ibits)], 1u);
    }

    bool inB = active && (iou > 0.4f);
    u32 m1 = 0u;
    if (inB) { m1 = jax_bits32(k1a, k1b, idx) >> 9; inB = (m1 >= BCUT); }
    s = wave_append_slot(&cB, inB, any);
    if (inB) lB[s] = ((u64)m1 << 25) | (u64)(0x1FFFFFFu - (idx + 128u));

    bool inC = active && (iou < 0.1f);
    u32 m3 = 0u;
    if (inC) { m3 = jax_bits32(k3a, k3b, idx) >> 9; inC = (m3 >= CCUT); }
    s = wave_append_slot(&cC, inC, any);
    if (inC) lC[s] = ((u64)m3 << 25) | (u64)(0x1FFFFFFu - idx);

    __syncthreads();  // makes cA/cB/cC reads uniform & LDS stores visible
    if (cA > LA_CAP - 256u) FLUSH(cA, lA, 0, bufA, capA);
    if (cB > LBC_CAP - 256u) FLUSH(cB, lB, 1, bufB, capB);
    if (cC > LBC_CAP - 256u) FLUSH(cC, lC, 2, bufC, capC);
  }
  FLUSH(cA, lA, 0, bufA, capA);
  FLUSH(cB, lB, 1, bufB, capB);
  FLUSH(cC, lC, 2, bufC, capC);
#undef FLUSH
  for (u32 b = tid; b < 1024u; b += 256u) {
    u32 v = hA[b];
    if (v) atomicAdd(&gHistA[b], v);
  }
}

// ---------------- K2: cut bin for top-128 IoU ----------------
__global__ __launch_bounds__(1024) void rpn_cut(const u32* __restrict__ gHistA,
                                                u32* __restrict__ counters) {
  __shared__ u32 sh[1024];
  u32 tid = threadIdx.x;
  sh[tid] = gHistA[tid];
  __syncthreads();
  for (u32 off = 1u; off < 1024u; off <<= 1) {
    u32 v = sh[tid];
    u32 a = (tid + off < 1024u) ? sh[tid + off] : 0u;
    __syncthreads();
    sh[tid] = v + a;
    __syncthreads();
  }
  // suffix sums; cut = max b with suffix[b] >= 128 (counters[4] pre-zeroed)
  if (sh[tid] >= 128u && (tid == 1023u || sh[tid + 1] < 128u))
    atomicMax(&counters[4], tid);
}

// ---------------- K3: compact top-IoU candidates ----------------
__global__ __launch_bounds__(256) void rpn_compactA(
    const u64* __restrict__ bufA, u32 capA, u64* __restrict__ bufTopA,
    u32* __restrict__ counters) {
  u32 nA = counters[0]; if (nA > capA) nA = capA;
  u32 cut = counters[4];
  for (u32 i = blockIdx.x * 256u + threadIdx.x; i < nA; i += gridDim.x * 256u) {
    u64 k = bufA[i];
    bool keep = iouBin((u32)(k >> 25)) >= cut;
    bool any;
    u32 s = wave_append_slot(&counters[3], keep, any);
    if (keep && s < TOPA_CAP) bufTopA[s] = k;
  }
}

// ---------------- K4: top-k selections + loss ----------------
__device__ inline void wave_max64(u64& k, u32& i) {
  for (int off = 32; off > 0; off >>= 1) {
    u64 ok = __shfl_xor(k, off, 64);
    u32 oi = __shfl_xor(i, off, 64);
    if (ok > k) { k = ok; i = oi; }
  }
}

// extract 128 largest keys (desc); key==0 is the empty sentinel
__device__ inline void extract128(u64* keyBuf, u32 nc, u64* redK, u32* redI,
                                  u64* selKey, u32 lane, u32 wid) {
  const u32 tid = threadIdx.x;
  for (u32 r = 0u; r < 128u; ++r) {
    u64 bk = 0ull; u32 bi = 0xFFFFFFFFu;
    for (u32 i = tid; i < nc; i += 1024u) {
      u64 k = keyBuf[i];
      if (k > bk) { bk = k; bi = i; }
    }
    wave_max64(bk, bi);
    if (lane == 0u) { redK[wid] = bk; redI[wid] = bi; }
    __syncthreads();
    if (wid == 0u) {
      u64 k2 = (lane < 16u) ? redK[lane] : 0ull;
      u32 i2 = (lane < 16u) ? redI[lane] : 0xFFFFFFFFu;
      wave_max64(k2, i2);
      if (lane == 0u) {
        selKey[r] = k2;
        if (k2 != 0ull && i2 != 0xFFFFFFFFu) keyBuf[i2] = 0ull;
      }
    }
    __syncthreads();
  }
}

// suffix-scan cut over a 1024-bin LDS histogram (destroys hist)
__device__ inline u32 block_sufcut(u32* hist, u32* s_tmp) {
  u32 tid = threadIdx.x;
  for (u32 off = 1u; off < 1024u; off <<= 1) {
    u32 v = hist[tid];
    u32 a = (tid + off < 1024u) ? hist[tid + off] : 0u;
    __syncthreads();
    hist[tid] = v + a;
    __syncthreads();
  }
  if (tid == 0u) *s_tmp = 0u;
  __syncthreads();
  if (hist[tid] >= 128u && (tid == 1023u || hist[tid + 1] < 128u))
    atomicMax(s_tmp, tid);
  __syncthreads();
  return *s_tmp;
}

__device__ inline u32 binB(u32 m) {  // phase-2 priority bins (window 2^17)
  return (m < BCUT) ? 0u : ((m - BCUT) >> 7);
}

__device__ inline float sl1(float d) {
  float ad = fabsf(d);
  return (ad < 1.0f) ? 0.5f * d * d : ad - 0.5f;
}

__global__ __launch_bounds__(1024) void rpn_finalize(
    const float* __restrict__ obj, const float4* __restrict__ props,
    const float4* __restrict__ gt,
    const u64* __restrict__ bufTopA,
    const u64* __restrict__ bufB, u32 capB,
    const u64* __restrict__ bufC, u32 capC,
    const u32* __restrict__ counters, float* __restrict__ out,
    u32 k2a, u32 k2b) {
  __shared__ u32 hist[1024];
  __shared__ u64 keyBuf[COMP_CAP];
  __shared__ u64 redK[16];
  __shared__ u32 redI[16];
  __shared__ u64 selKey[128];
  __shared__ u32 bestIdx[128];
  __shared__ float fred[1024];
  __shared__ u32 s_cnt, s_tmp;
  __shared__ float s_reg, s_bcep;

  const u32 tid = threadIdx.x;
  const u32 lane = tid & 63u;
  const u32 wid = tid >> 6;
  const u32 nB = counters[1] < capB ? counters[1] : capB;
  const u32 nC = counters[2] < capC ? counters[2] : capC;
  const u32 nT = counters[3] < TOPA_CAP ? counters[3] : TOPA_CAP;

  // ===== Phase 1: best_idx = top-128 of flat IoU (desc, ties idx asc) =====
  for (u32 i = tid; i < nT; i += 1024u) keyBuf[i] = bufTopA[i];
  __syncthreads();
  extract128(keyBuf, nT, redK, redI, selKey, lane, wid);
  if (tid < 128u) {
    u64 k = selKey[tid];
    bestIdx[tid] = (k == 0ull) ? 0u : (0x1FFFFFFu - (u32)(k & 0x1FFFFFFu));
  }
  __syncthreads();

  // ===== Phase 2: positives = top-128 of [best_prio(128) ++ pos_prio] =====
  for (u32 i = tid; i < 1024u; i += 1024u) hist[i] = 0u;
  __syncthreads();
  u32 myM2 = 0u, myBin = 0u;
  if (tid < 128u) {
    myM2 = jax_bits32(k2a, k2b, tid) >> 9;
    myBin = binB(myM2);
    atomicAdd(&hist[myBin], 1u);
  }
  for (u32 i = tid; i < nB; i += 1024u)
    atomicAdd(&hist[binB((u32)(bufB[i] >> 25))], 1u);
  __syncthreads();
  u32 cut = block_sufcut(hist, &s_tmp);
  if (tid == 0u) s_cnt = 0u;
  __syncthreads();
  if (tid < 128u && myBin >= cut) {
    u32 s = atomicAdd(&s_cnt, 1u);
    if (s < COMP_CAP) keyBuf[s] = ((u64)myM2 << 25) | (u64)(0x1FFFFFFu - tid);
  }
  for (u32 i = tid; i < nB; i += 1024u) {
    u64 k = bufB[i];
    if (binB((u32)(k >> 25)) >= cut) {
      u32 s = atomicAdd(&s_cnt, 1u);
      if (s < COMP_CAP) keyBuf[s] = k;
    }
  }
  __syncthreads();
  u32 nc = s_cnt < COMP_CAP ? s_cnt : COMP_CAP;
  extract128(keyBuf, nc, redK, redI, selKey, lane, wid);

  float locReg = 0.0f, locBce = 0.0f;
  if (tid < 128u) {
    u64 k = selKey[tid];
    if (k != 0ull) {
      u32 c = 0x1FFFFFFu - (u32)(k & 0x1FFFFFFu);
      u32 pair = (c < 128u) ? bestIdx[c] : (c - 128u);
      if (pair < NM) {
        u32 row = pair / M_PROP, col = pair % M_PROP;
        float4 pr = props[col];
        float4 gb = gt[row];
        locReg = sl1(pr.x - gb.x) + sl1(pr.y - gb.y) +
                 sl1(pr.z - gb.z) + sl1(pr.w - gb.w);
        float l = obj[col];
        locBce = fmaxf(l, 0.0f) - l + log1pf(expf(-fabsf(l)));
      }
    }
  }
  fred[tid] = locReg; __syncthreads();
  for (u32 off = 512u; off > 0u; off >>= 1) { if (tid < off) fred[tid] += fred[tid + off]; __syncthreads(); }
  if (tid == 0u) s_reg = fred[0];
  __syncthreads();
  fred[tid] = locBce; __syncthreads();
  for (u32 off = 512u; off > 0u; off >>= 1) { if (tid < off) fred[tid] += fred[tid + off]; __syncthreads(); }
  if (tid == 0u) s_bcep = fred[0];
  __syncthreads();

  // ===== Phase 3: negatives = top-128 of neg_prio =====
  for (u32 i = tid; i < 1024u; i += 1024u) hist[i] = 0u;
  __syncthreads();
  for (u32 i = tid; i < nC; i += 1024u) {
    u32 m = (u32)(bufC[i] >> 25);
    atomicAdd(&hist[(m & 0xFFFu) >> 2], 1u);  // m in [2^23-2^12, 2^23)
  }
  __syncthreads();
  cut = block_sufcut(hist, &s_tmp);
  if (tid == 0u) s_cnt = 0u;
  __syncthreads();
  for (u32 i = tid; i < nC; i += 1024u) {
    u64 k = bufC[i];
    u32 m = (u32)(k >> 25);
    if (((m & 0xFFFu) >> 2) >= cut) {
      u32 s = atomicAdd(&s_cnt, 1u);
      if (s < COMP_CAP) keyBuf[s] = k;
    }
  }
  __syncthreads();
  nc = s_cnt < COMP_CAP ? s_cnt : COMP_CAP;
  extract128(keyBuf, nc, redK, redI, selKey, lane, wid);

  float locBceN = 0.0f;
  if (tid < 128u) {
    u64 k = selKey[tid];
    if (k != 0ull) {
      u32 idx = 0x1FFFFFFu - (u32)(k & 0x1FFFFFFu);
      u32 col = idx % M_PROP;
      float l = obj[col];
      locBceN = fmaxf(l, 0.0f) + log1pf(expf(-fabsf(l)));
    }
  }
  fred[tid] = locBceN; __syncthreads();
  for (u32 off = 512u; off > 0u; off >>= 1) { if (tid < off) fred[tid] += fred[tid + off]; __syncthreads(); }
  if (tid == 0u) {
    float cls = (s_bcep + fred[0]) / 256.0f;
    float reg = s_reg / 512.0f;
    out[0] = cls + 10.0f * reg;
  }
}

extern "C" void kernel_launch(void* const* d_in, const int* in_sizes, int n_in,
                              void* d_out, int out_size, void* d_ws, size_t ws_size,
                              hipStream_t stream) {
  (void)in_sizes; (void)n_in; (void)out_size;
  const float* obj = (const float*)d_in[0];
  const float4* props = (const float4*)d_in[1];
  const float4* gt = (const float4*)d_in[2];
  float* out = (float*)d_out;

  u32 k1a, k1b, k2a, k2b, k3a, k3b;
  jax_split3(k1a, k1b, k2a, k2b, k3a, k3b);

  // d_ws layout: counters(256B) | gHistA(4KB) | bufTopA(64KB) | bufB | bufC | bufA
  uint8_t* base = (uint8_t*)d_ws;
  u32* counters = (u32*)base;
  u32* gHistA = (u32*)(base + 256);
  u64* bufTopA = (u64*)(base + 256 + 4096);
  size_t fixed = 256 + 4096 + (size_t)TOPA_CAP * 8;
  size_t capB = 65536, capC = 65536;
  size_t capA = 4194304;
  size_t avail = ws_size > fixed ? ws_size - fixed : 0;
  size_t needBC = (capB + capC) * 8;
  if (avail < needBC + capA * 8) {
    size_t left = avail > needBC ? avail - needBC : 0;
    capA = left / 8;
  }
  u64* bufB = (u64*)(base + fixed);
  u64* bufC = (u64*)(base + fixed + capB * 8);
  u64* bufA = (u64*)(base + fixed + capB * 8 + capC * 8);

  rpn_init<<<1, 256, 0, stream>>>(counters, gHistA);
  rpn_collect<<<(M_PROP + 255) / 256, 256, 0, stream>>>(
      props, gt, bufA, (u32)capA, bufB, (u32)capB, bufC, (u32)capC,
      counters, gHistA, k1a, k1b, k3a, k3b);
  rpn_cut<<<1, 1024, 0, stream>>>(gHistA, counters);
  rpn_compactA<<<128, 256, 0, stream>>>(bufA, (u32)capA, bufTopA, counters);
  rpn_finalize<<<1, 1024, 0, stream>>>(
      obj, props, gt, bufTopA, bufB, (u32)capB, bufC, (u32)capC,
      counters, out, k2a, k2b);
}

// Round 4
// 233.295 us; speedup vs baseline: 9.6135x; 2.9847x over previous
//
#include <hip/hip_runtime.h>
#include <stdint.h>

// All FP must match XLA's HLO op-for-op: no mul+add contraction.
#pragma clang fp contract(off)

typedef unsigned long long u64;
typedef uint32_t u32;

#define M_PROP 200000u
#define N_GT   128u
#define NM     25600000u

// priority cuts (23-bit priorities):
//  B: pos pairs (iou>0.4, ~500k) with m1 >= 2^23-2^17 -> ~7.8k kept; since
//     #kept >= 128, the true top-128 pos-priority keys are all kept (exact).
//  C: neg pairs (iou<0.1, ~25.1M) with m3 >= 2^23-2^12 -> ~12.3k kept.
#define BCUT 8257536u   // 2^23 - 2^17
#define CCUT 8384512u   // 2^23 - 2^12

#define LA_CAP 3072u
#define LBC_CAP 512u
#define TOPA_CAP 8192u
#define COMP_CAP 8192u

// counters slots: 0=cntA 1=cntB 2=cntC 3=cntTopA 4=cutA
// ---------------- threefry2x32 (20 rounds) ----------------
__host__ __device__ inline void tf2x32(u32 k0, u32 k1, u32 x0, u32 x1,
                                       u32& o0, u32& o1) {
  u32 ks0 = k0, ks1 = k1, ks2 = k0 ^ k1 ^ 0x1BD11BDAu;
  x0 += ks0; x1 += ks1;
#define TF_R(r) { x0 += x1; x1 = (x1 << r) | (x1 >> (32 - r)); x1 ^= x0; }
  TF_R(13) TF_R(15) TF_R(26) TF_R(6)
  x0 += ks1; x1 += ks2 + 1u;
  TF_R(17) TF_R(29) TF_R(16) TF_R(24)
  x0 += ks2; x1 += ks0 + 2u;
  TF_R(13) TF_R(15) TF_R(26) TF_R(6)
  x0 += ks0; x1 += ks1 + 3u;
  TF_R(17) TF_R(29) TF_R(16) TF_R(24)
  x0 += ks1; x1 += ks2 + 4u;
  TF_R(13) TF_R(15) TF_R(26) TF_R(6)
  x0 += ks2; x1 += ks0 + 5u;
#undef TF_R
  o0 = x0; o1 = x1;
}

// partitionable threefry: 32 bits for element idx
__device__ inline u32 jax_bits32(u32 ka, u32 kb, u32 idx) {
  u32 a, b; tf2x32(ka, kb, 0u, idx, a, b);
  return a ^ b;
}

static void jax_split3(u32& k1a, u32& k1b, u32& k2a, u32& k2b,
                       u32& k3a, u32& k3b) {
  const u32 K0 = 0u, K1 = 42u;
  tf2x32(K0, K1, 0u, 0u, k1a, k1b);
  tf2x32(K0, K1, 0u, 1u, k2a, k2b);
  tf2x32(K0, K1, 0u, 2u, k3a, k3b);
}

// wave-aggregated append (one atomic per wave per predicate)
__device__ inline u32 wave_append_slot(u32* ctr, bool pred, bool& any) {
  u64 mask = __ballot(pred);
  if (mask == 0ull) { any = false; return 0u; }
  any = true;
  u32 lane = threadIdx.x & 63u;
  u32 prefix = (u32)__popcll(mask & ((1ull << lane) - 1ull));
  int leader = __ffsll(mask) - 1;
  u32 base = 0u;
  if ((int)lane == leader) base = atomicAdd(ctr, (u32)__popcll(mask));
  base = __shfl(base, leader, 64);
  return base + prefix;
}

__device__ inline u32 iouBin(u32 bits) {  // monotone bins over (0.25, 1.0]
  u32 b = (bits - 0x3E800000u) >> 14;
  return b > 1023u ? 1023u : b;
}

// ---------------- K0: zero counters + global histogram ----------------
__global__ __launch_bounds__(256) void rpn_init(u32* counters, u32* gHistA) {
  u32 tid = threadIdx.x;
  if (tid < 64u) counters[tid] = 0u;
  for (u32 i = tid; i < 1024u; i += 256u) gHistA[i] = 0u;
}

// ---------------- K1: IoU + filtered candidate collection ----------------
__global__ __launch_bounds__(256) void rpn_collect(
    const float4* __restrict__ props, const float4* __restrict__ gt,
    u64* __restrict__ bufA, u32 capA,
    u64* __restrict__ bufB, u32 capB,
    u64* __restrict__ bufC, u32 capC,
    u32* __restrict__ counters, u32* __restrict__ gHistA,
    u32 k1a, u32 k1b, u32 k3a, u32 k3b) {
  __shared__ float4 gtS[N_GT];
  __shared__ u64 lA[LA_CAP];
  __shared__ u64 lB[LBC_CAP];
  __shared__ u64 lC[LBC_CAP];
  __shared__ u32 hA[1024];
  __shared__ u32 cA, cB, cC, flushBase;

  const u32 tid = threadIdx.x;
  for (u32 i = tid; i < 1024u; i += 256u) hA[i] = 0u;
  for (u32 j = tid; j < N_GT; j += 256u) gtS[j] = gt[j];
  if (tid == 0u) { cA = 0u; cB = 0u; cC = 0u; }
  __syncthreads();

  u32 p = blockIdx.x * 256u + tid;
  bool active = p < M_PROP;
  float4 pb = make_float4(0.f, 0.f, 0.f, 0.f);
  if (active) pb = props[p];
  float pa = (pb.z - pb.x) * (pb.w - pb.y);

#define FLUSH(cX, lX, ctrIdx, bufX, capX)                                   \
  {                                                                          \
    if (tid == 0u) flushBase = atomicAdd(&counters[ctrIdx], cX);             \
    __syncthreads();                                                         \
    for (u32 i = tid; i < cX; i += 256u) {                                   \
      u32 d = flushBase + i;                                                 \
      if (d < capX) bufX[d] = lX[i];                                         \
    }                                                                        \
    __syncthreads();                                                         \
    if (tid == 0u) cX = 0u;                                                  \
    __syncthreads();                                                         \
  }

  for (u32 g = 0u; g < N_GT; ++g) {
    float4 gb = gtS[g];
    float ga = (gb.z - gb.x) * (gb.w - gb.y);
    float wx = fminf(gb.z, pb.z) - fmaxf(gb.x, pb.x);
    float wy = fminf(gb.w, pb.w) - fmaxf(gb.y, pb.y);
    wx = fmaxf(wx, 0.0f); wy = fmaxf(wy, 0.0f);
    float inter = wx * wy;
    float iou = inter / (ga + pa - inter);
    u32 idx = g * M_PROP + p;
    u32 ibits = __float_as_uint(iou);

    bool inA = active && (iou > 0.25f);
    bool any; u32 s;
    s = wave_append_slot(&cA, inA, any);
    if (inA) {
      lA[s] = ((u64)ibits << 25) | (u64)(0x1FFFFFFu - idx);
      atomicAdd(&hA[iouBin(ibits)], 1u);
    }

    bool inB = active && (iou > 0.4f);
    u32 m1 = 0u;
    if (inB) { m1 = jax_bits32(k1a, k1b, idx) >> 9; inB = (m1 >= BCUT); }
    s = wave_append_slot(&cB, inB, any);
    if (inB) lB[s] = ((u64)m1 << 25) | (u64)(0x1FFFFFFu - (idx + 128u));

    bool inC = active && (iou < 0.1f);
    u32 m3 = 0u;
    if (inC) { m3 = jax_bits32(k3a, k3b, idx) >> 9; inC = (m3 >= CCUT); }
    s = wave_append_slot(&cC, inC, any);
    if (inC) lC[s] = ((u64)m3 << 25) | (u64)(0x1FFFFFFu - idx);

    __syncthreads();  // makes cA/cB/cC reads uniform & LDS stores visible
    if (cA > LA_CAP - 256u) FLUSH(cA, lA, 0, bufA, capA);
    if (cB > LBC_CAP - 256u) FLUSH(cB, lB, 1, bufB, capB);
    if (cC > LBC_CAP - 256u) FLUSH(cC, lC, 2, bufC, capC);
  }
  FLUSH(cA, lA, 0, bufA, capA);
  FLUSH(cB, lB, 1, bufB, capB);
  FLUSH(cC, lC, 2, bufC, capC);
#undef FLUSH
  for (u32 b = tid; b < 1024u; b += 256u) {
    u32 v = hA[b];
    if (v) atomicAdd(&gHistA[b], v);
  }
}

// ---------------- K2: cut bin for top-128 IoU ----------------
__global__ __launch_bounds__(1024) void rpn_cut(const u32* __restrict__ gHistA,
                                                u32* __restrict__ counters) {
  __shared__ u32 sh[1024];
  u32 tid = threadIdx.x;
  sh[tid] = gHistA[tid];
  __syncthreads();
  for (u32 off = 1u; off < 1024u; off <<= 1) {
    u32 v = sh[tid];
    u32 a = (tid + off < 1024u) ? sh[tid + off] : 0u;
    __syncthreads();
    sh[tid] = v + a;
    __syncthreads();
  }
  // suffix sums; cut = max b with suffix[b] >= 128 (counters[4] pre-zeroed)
  if (sh[tid] >= 128u && (tid == 1023u || sh[tid + 1] < 128u))
    atomicMax(&counters[4], tid);
}

// ---------------- K3: compact top-IoU candidates ----------------
__global__ __launch_bounds__(256) void rpn_compactA(
    const u64* __restrict__ bufA, u32 capA, u64* __restrict__ bufTopA,
    u32* __restrict__ counters) {
  u32 nA = counters[0]; if (nA > capA) nA = capA;
  u32 cut = counters[4];
  for (u32 i = blockIdx.x * 256u + threadIdx.x; i < nA; i += gridDim.x * 256u) {
    u64 k = bufA[i];
    bool keep = iouBin((u32)(k >> 25)) >= cut;
    bool any;
    u32 s = wave_append_slot(&counters[3], keep, any);
    if (keep && s < TOPA_CAP) bufTopA[s] = k;
  }
}

// ---------------- K4: rank-select + loss ----------------
// One-pass exact top-128 (desc) of nc distinct keys, nc <= 8192.
// Each thread owns up to 8 keys; rank = #{keys greater}; rank<128 writes.
// Caller must __syncthreads() after filling cand. selKey[i]==0 => empty.
__device__ inline void rank_select(const u64* cand, u32 nc, u64* selKey) {
  const u32 tid = threadIdx.x;
  if (tid < 128u) selKey[tid] = 0ull;
  u64 k[8]; u32 r[8];
#pragma unroll
  for (int j = 0; j < 8; ++j) {
    u32 i = tid + (u32)j * 1024u;
    k[j] = (i < nc) ? cand[i] : 0ull;
    r[j] = 0u;
  }
  __syncthreads();
  for (u32 i = 0u; i < nc; ++i) {
    u64 v = cand[i];
#pragma unroll
    for (int j = 0; j < 8; ++j) r[j] += (v > k[j]) ? 1u : 0u;
  }
#pragma unroll
  for (int j = 0; j < 8; ++j) {
    u32 i = tid + (u32)j * 1024u;
    if (i < nc && r[j] < 128u) selKey[r[j]] = k[j];
  }
  __syncthreads();
}

// suffix-scan cut over a 1024-bin LDS histogram (destroys hist)
__device__ inline u32 block_sufcut(u32* hist, u32* s_tmp) {
  u32 tid = threadIdx.x;
  for (u32 off = 1u; off < 1024u; off <<= 1) {
    u32 v = hist[tid];
    u32 a = (tid + off < 1024u) ? hist[tid + off] : 0u;
    __syncthreads();
    hist[tid] = v + a;
    __syncthreads();
  }
  if (tid == 0u) *s_tmp = 0u;
  __syncthreads();
  if (hist[tid] >= 128u && (tid == 1023u || hist[tid + 1] < 128u))
    atomicMax(s_tmp, tid);
  __syncthreads();
  return *s_tmp;
}

__device__ inline u32 binB(u32 m) {  // phase-2 priority bins (window 2^17)
  return (m < BCUT) ? 0u : ((m - BCUT) >> 7);
}

__device__ inline float sl1(float d) {
  float ad = fabsf(d);
  return (ad < 1.0f) ? 0.5f * d * d : ad - 0.5f;
}

__global__ __launch_bounds__(1024) void rpn_finalize(
    const float* __restrict__ obj, const float4* __restrict__ props,
    const float4* __restrict__ gt,
    const u64* __restrict__ bufTopA,
    const u64* __restrict__ bufB, u32 capB,
    const u64* __restrict__ bufC, u32 capC,
    const u32* __restrict__ counters, float* __restrict__ out,
    u32 k2a, u32 k2b) {
  __shared__ u32 hist[1024];
  __shared__ u64 keyBuf[COMP_CAP];
  __shared__ u64 selKey[128];
  __shared__ u32 bestIdx[128];
  __shared__ float fred[1024];
  __shared__ u32 s_cnt, s_tmp;
  __shared__ float s_reg, s_bcep;

  const u32 tid = threadIdx.x;
  const u32 nB = counters[1] < capB ? counters[1] : capB;
  const u32 nC = counters[2] < capC ? counters[2] : capC;
  const u32 nT = counters[3] < TOPA_CAP ? counters[3] : TOPA_CAP;

  // ===== Phase 1: best_idx = top-128 of flat IoU (desc, ties idx asc) =====
  for (u32 i = tid; i < nT; i += 1024u) keyBuf[i] = bufTopA[i];
  __syncthreads();
  rank_select(keyBuf, nT, selKey);
  if (tid < 128u) {
    u64 k = selKey[tid];
    bestIdx[tid] = (k == 0ull) ? 0u : (0x1FFFFFFu - (u32)(k & 0x1FFFFFFu));
  }
  __syncthreads();

  // ===== Phase 2: positives = top-128 of [best_prio(128) ++ pos_prio] =====
  for (u32 i = tid; i < 1024u; i += 1024u) hist[i] = 0u;
  __syncthreads();
  u32 myM2 = 0u, myBin = 0u;
  if (tid < 128u) {
    myM2 = jax_bits32(k2a, k2b, tid) >> 9;
    myBin = binB(myM2);
    atomicAdd(&hist[myBin], 1u);
  }
  for (u32 i = tid; i < nB; i += 1024u)
    atomicAdd(&hist[binB((u32)(bufB[i] >> 25))], 1u);
  __syncthreads();
  u32 cut = block_sufcut(hist, &s_tmp);
  if (tid == 0u) s_cnt = 0u;
  __syncthreads();
  if (tid < 128u && myBin >= cut) {
    u32 s = atomicAdd(&s_cnt, 1u);
    if (s < COMP_CAP) keyBuf[s] = ((u64)myM2 << 25) | (u64)(0x1FFFFFFu - tid);
  }
  for (u32 i = tid; i < nB; i += 1024u) {
    u64 k = bufB[i];
    if (binB((u32)(k >> 25)) >= cut) {
      u32 s = atomicAdd(&s_cnt, 1u);
      if (s < COMP_CAP) keyBuf[s] = k;
    }
  }
  __syncthreads();
  u32 nc = s_cnt < COMP_CAP ? s_cnt : COMP_CAP;
  rank_select(keyBuf, nc, selKey);

  float locReg = 0.0f, locBce = 0.0f;
  if (tid < 128u) {
    u64 k = selKey[tid];
    if (k != 0ull) {
      u32 c = 0x1FFFFFFu - (u32)(k & 0x1FFFFFFu);
      u32 pair = (c < 128u) ? bestIdx[c] : (c - 128u);
      if (pair < NM) {
        u32 row = pair / M_PROP, col = pair % M_PROP;
        float4 pr = props[col];
        float4 gb = gt[row];
        locReg = sl1(pr.x - gb.x) + sl1(pr.y - gb.y) +
                 sl1(pr.z - gb.z) + sl1(pr.w - gb.w);
        float l = obj[col];
        locBce = fmaxf(l, 0.0f) - l + log1pf(expf(-fabsf(l)));
      }
    }
  }
  fred[tid] = locReg; __syncthreads();
  for (u32 off = 512u; off > 0u; off >>= 1) { if (tid < off) fred[tid] += fred[tid + off]; __syncthreads(); }
  if (tid == 0u) s_reg = fred[0];
  __syncthreads();
  fred[tid] = locBce; __syncthreads();
  for (u32 off = 512u; off > 0u; off >>= 1) { if (tid < off) fred[tid] += fred[tid + off]; __syncthreads(); }
  if (tid == 0u) s_bcep = fred[0];
  __syncthreads();

  // ===== Phase 3: negatives = top-128 of neg_prio =====
  for (u32 i = tid; i < 1024u; i += 1024u) hist[i] = 0u;
  __syncthreads();
  for (u32 i = tid; i < nC; i += 1024u) {
    u32 m = (u32)(bufC[i] >> 25);
    atomicAdd(&hist[(m & 0xFFFu) >> 2], 1u);  // m in [2^23-2^12, 2^23)
  }
  __syncthreads();
  cut = block_sufcut(hist, &s_tmp);
  if (tid == 0u) s_cnt = 0u;
  __syncthreads();
  for (u32 i = tid; i < nC; i += 1024u) {
    u64 k = bufC[i];
    u32 m = (u32)(k >> 25);
    if (((m & 0xFFFu) >> 2) >= cut) {
      u32 s = atomicAdd(&s_cnt, 1u);
      if (s < COMP_CAP) keyBuf[s] = k;
    }
  }
  __syncthreads();
  nc = s_cnt < COMP_CAP ? s_cnt : COMP_CAP;
  rank_select(keyBuf, nc, selKey);

  float locBceN = 0.0f;
  if (tid < 128u) {
    u64 k = selKey[tid];
    if (k != 0ull) {
      u32 idx = 0x1FFFFFFu - (u32)(k & 0x1FFFFFFu);
      u32 col = idx % M_PROP;
      float l = obj[col];
      locBceN = fmaxf(l, 0.0f) + log1pf(expf(-fabsf(l)));
    }
  }
  fred[tid] = locBceN; __syncthreads();
  for (u32 off = 512u; off > 0u; off >>= 1) { if (tid < off) fred[tid] += fred[tid + off]; __syncthreads(); }
  if (tid == 0u) {
    float cls = (s_bcep + fred[0]) / 256.0f;
    float reg = s_reg / 512.0f;
    out[0] = cls + 10.0f * reg;
  }
}

extern "C" void kernel_launch(void* const* d_in, const int* in_sizes, int n_in,
                              void* d_out, int out_size, void* d_ws, size_t ws_size,
                              hipStream_t stream) {
  (void)in_sizes; (void)n_in; (void)out_size;
  const float* obj = (const float*)d_in[0];
  const float4* props = (const float4*)d_in[1];
  const float4* gt = (const float4*)d_in[2];
  float* out = (float*)d_out;

  u32 k1a, k1b, k2a, k2b, k3a, k3b;
  jax_split3(k1a, k1b, k2a, k2b, k3a, k3b);

  // d_ws layout: counters(256B) | gHistA(4KB) | bufTopA(64KB) | bufB | bufC | bufA
  uint8_t* base = (uint8_t*)d_ws;
  u32* counters = (u32*)base;
  u32* gHistA = (u32*)(base + 256);
  u64* bufTopA = (u64*)(base + 256 + 4096);
  size_t fixed = 256 + 4096 + (size_t)TOPA_CAP * 8;
  size_t capB = 65536, capC = 65536;
  size_t capA = 4194304;
  size_t avail = ws_size > fixed ? ws_size - fixed : 0;
  size_t needBC = (capB + capC) * 8;
  if (avail < needBC + capA * 8) {
    size_t left = avail > needBC ? avail - needBC : 0;
    capA = left / 8;
  }
  u64* bufB = (u64*)(base + fixed);
  u64* bufC = (u64*)(base + fixed + capB * 8);
  u64* bufA = (u64*)(base + fixed + capB * 8 + capC * 8);

  rpn_init<<<1, 256, 0, stream>>>(counters, gHistA);
  rpn_collect<<<(M_PROP + 255) / 256, 256, 0, stream>>>(
      props, gt, bufA, (u32)capA, bufB, (u32)capB, bufC, (u32)capC,
      counters, gHistA, k1a, k1b, k3a, k3b);
  rpn_cut<<<1, 1024, 0, stream>>>(gHistA, counters);
  rpn_compactA<<<128, 256, 0, stream>>>(bufA, (u32)capA, bufTopA, counters);
  rpn_finalize<<<1, 1024, 0, stream>>>(
      obj, props, gt, bufTopA, bufB, (u32)capB, bufC, (u32)capC,
      counters, out, k2a, k2b);
}

// Round 5
// 228.736 us; speedup vs baseline: 9.8051x; 1.0199x over previous
//
#include <hip/hip_runtime.h>
#include <stdint.h>

// All FP must match XLA's HLO op-for-op: no mul+add contraction.
#pragma clang fp contract(off)

typedef unsigned long long u64;
typedef uint32_t u32;

#define M_PROP 200000u
#define N_GT   128u
#define NM     25600000u

// priority cuts (23-bit priorities):
//  B: pos pairs (iou>0.4, ~500k) with m1 >= 2^23-2^17 -> ~7.8k kept; since
//     #kept >= 128, the true top-128 pos-priority keys are all kept (exact).
//  C: neg pairs (iou<0.1, ~25.1M) with m3 >= 2^23-2^12 -> ~12.3k kept.
#define BCUT 8257536u   // 2^23 - 2^17
#define CCUT 8384512u   // 2^23 - 2^12

#define SHARDS 16u
#define SHARD_CAP 4096u
#define TOPA_CAP 8192u
#define COMP_CAP 8192u
#define BCAP 768u        // per-wave B-precandidate LDS staging

// counters slots: 3=cntTopA 4=cutA 8..23=C shard counts 24..39=B shard counts

// ---------------- threefry2x32 (20 rounds) ----------------
__host__ __device__ inline void tf2x32(u32 k0, u32 k1, u32 x0, u32 x1,
                                       u32& o0, u32& o1) {
  u32 ks0 = k0, ks1 = k1, ks2 = k0 ^ k1 ^ 0x1BD11BDAu;
  x0 += ks0; x1 += ks1;
#define TF_R(r) { x0 += x1; x1 = (x1 << r) | (x1 >> (32 - r)); x1 ^= x0; }
  TF_R(13) TF_R(15) TF_R(26) TF_R(6)
  x0 += ks1; x1 += ks2 + 1u;
  TF_R(17) TF_R(29) TF_R(16) TF_R(24)
  x0 += ks2; x1 += ks0 + 2u;
  TF_R(13) TF_R(15) TF_R(26) TF_R(6)
  x0 += ks0; x1 += ks1 + 3u;
  TF_R(17) TF_R(29) TF_R(16) TF_R(24)
  x0 += ks1; x1 += ks2 + 4u;
  TF_R(13) TF_R(15) TF_R(26) TF_R(6)
  x0 += ks2; x1 += ks0 + 5u;
#undef TF_R
  o0 = x0; o1 = x1;
}

// partitionable threefry: 32 bits for element idx
__device__ inline u32 jax_bits32(u32 ka, u32 kb, u32 idx) {
  u32 a, b; tf2x32(ka, kb, 0u, idx, a, b);
  return a ^ b;
}

static void jax_split3(u32& k1a, u32& k1b, u32& k2a, u32& k2b,
                       u32& k3a, u32& k3b) {
  const u32 K0 = 0u, K1 = 42u;
  tf2x32(K0, K1, 0u, 0u, k1a, k1b);
  tf2x32(K0, K1, 0u, 1u, k2a, k2b);
  tf2x32(K0, K1, 0u, 2u, k3a, k3b);
}

// wave-aggregated append (one atomic per wave per predicate)
__device__ inline u32 wave_append_slot(u32* ctr, bool pred, bool& any) {
  u64 mask = __ballot(pred);
  if (mask == 0ull) { any = false; return 0u; }
  any = true;
  u32 lane = threadIdx.x & 63u;
  u32 prefix = (u32)__popcll(mask & ((1ull << lane) - 1ull));
  int leader = __ffsll(mask) - 1;
  u32 base = 0u;
  if ((int)lane == leader) base = atomicAdd(ctr, (u32)__popcll(mask));
  base = __shfl(base, leader, 64);
  return base + prefix;
}

__device__ inline u32 iouBin(u32 bits) {  // monotone bins over (0.25, 1.0]
  u32 b = (bits - 0x3E800000u) >> 14;
  return b > 1023u ? 1023u : b;
}

// ---------------- K0: zero counters + global histogram ----------------
__global__ __launch_bounds__(256) void rpn_init(u32* counters, u32* gHistA) {
  u32 tid = threadIdx.x;
  if (tid < 64u) counters[tid] = 0u;
  for (u32 i = tid; i < 1024u; i += 256u) gHistA[i] = 0u;
}

// ---------------- K1: IoU + hist + B/C candidate collection ----------------
__global__ __launch_bounds__(256) void rpn_collect(
    const float4* __restrict__ props, const float4* __restrict__ gt,
    u64* __restrict__ bufB, u64* __restrict__ bufC,
    u32* __restrict__ counters, u32* __restrict__ gHistA,
    u32 k1a, u32 k1b, u32 k3a, u32 k3b) {
  __shared__ float4 gtS[N_GT];
  __shared__ u32 hA[1024];
  __shared__ u32 listB[4][BCAP];
  const u32 tid = threadIdx.x;
  const u32 lane = tid & 63u;
  const u32 wid = tid >> 6;
  for (u32 i = tid; i < 1024u; i += 256u) hA[i] = 0u;
  for (u32 j = tid; j < N_GT; j += 256u) gtS[j] = gt[j];
  __syncthreads();

  const u32 shard = blockIdx.x & (SHARDS - 1u);
  u32* cntC_g = &counters[8u + shard];
  u32* cntB_g = &counters[24u + shard];
  u64* myBufC = bufC + (size_t)shard * SHARD_CAP;
  u64* myBufB = bufB + (size_t)shard * SHARD_CAP;

  u32 p = blockIdx.x * 256u + tid;
  bool active = p < M_PROP;
  float4 pb = make_float4(0.f, 0.f, 0.f, 0.f);
  if (active) pb = props[p];
  float pa = (pb.z - pb.x) * (pb.w - pb.y);

  u32 cntB = 0u;  // wave-uniform (derived from ballots only)
  const u64 laneLT = (1ull << lane) - 1ull;

#define PROCESS_B()                                                          \
  {                                                                          \
    for (u32 i = lane; i < cntB; i += 64u) {                                 \
      u32 bidx = listB[wid][i];                                              \
      u32 m1 = jax_bits32(k1a, k1b, bidx) >> 9;                              \
      bool keep = m1 >= BCUT;                                                \
      bool anyk;                                                             \
      u32 sk = wave_append_slot(cntB_g, keep, anyk);                         \
      if (keep && sk < SHARD_CAP)                                            \
        myBufB[sk] = ((u64)m1 << 25) | (u64)(0x1FFFFFFu - (bidx + 128u));    \
    }                                                                        \
    cntB = 0u;                                                               \
  }

  for (u32 g = 0u; g < N_GT; g += 2u) {
    float4 g0 = gtS[g];
    float4 g1 = gtS[g + 1u];
    float ga0 = (g0.z - g0.x) * (g0.w - g0.y);
    float wx0 = fminf(g0.z, pb.z) - fmaxf(g0.x, pb.x);
    float wy0 = fminf(g0.w, pb.w) - fmaxf(g0.y, pb.y);
    wx0 = fmaxf(wx0, 0.0f); wy0 = fmaxf(wy0, 0.0f);
    float in0 = wx0 * wy0;
    float iou0 = in0 / (ga0 + pa - in0);
    float ga1 = (g1.z - g1.x) * (g1.w - g1.y);
    float wx1 = fminf(g1.z, pb.z) - fmaxf(g1.x, pb.x);
    float wy1 = fminf(g1.w, pb.w) - fmaxf(g1.y, pb.y);
    wx1 = fmaxf(wx1, 0.0f); wy1 = fmaxf(wy1, 0.0f);
    float in1 = wx1 * wy1;
    float iou1 = in1 / (ga1 + pa - in1);
    u32 idx0 = g * M_PROP + p;
    u32 idx1 = idx0 + M_PROP;

    // two independent threefry chains, unconditional (98% needed anyway)
    u32 m30 = jax_bits32(k3a, k3b, idx0) >> 9;
    u32 m31 = jax_bits32(k3a, k3b, idx1) >> 9;

    // A histogram (LDS atomics; rare)
    if (active && iou0 > 0.25f)
      atomicAdd(&hA[iouBin(__float_as_uint(iou0))], 1u);
    if (active && iou1 > 0.25f)
      atomicAdd(&hA[iouBin(__float_as_uint(iou1))], 1u);

    // C: direct sharded global append
    bool c0 = active && (iou0 < 0.1f) && (m30 >= CCUT);
    bool c1 = active && (iou1 < 0.1f) && (m31 >= CCUT);
    bool any; u32 s;
    s = wave_append_slot(cntC_g, c0, any);
    if (c0 && s < SHARD_CAP)
      myBufC[s] = ((u64)m30 << 25) | (u64)(0x1FFFFFFu - idx0);
    s = wave_append_slot(cntC_g, c1, any);
    if (c1 && s < SHARD_CAP)
      myBufC[s] = ((u64)m31 << 25) | (u64)(0x1FFFFFFu - idx1);

    // B: stage idx into per-wave LDS list (dense threefry later)
    bool b0 = active && (iou0 > 0.4f);
    u64 mb0 = __ballot(b0);
    if (mb0) {
      u32 pfx = (u32)__popcll(mb0 & laneLT);
      if (b0) listB[wid][cntB + pfx] = idx0;
      cntB += (u32)__popcll(mb0);
    }
    bool b1 = active && (iou1 > 0.4f);
    u64 mb1 = __ballot(b1);
    if (mb1) {
      u32 pfx = (u32)__popcll(mb1 & laneLT);
      if (b1) listB[wid][cntB + pfx] = idx1;
      cntB += (u32)__popcll(mb1);
    }
    if (cntB > BCAP - 128u) PROCESS_B();
  }
  PROCESS_B();
#undef PROCESS_B

  __syncthreads();
  for (u32 b = tid; b < 1024u; b += 256u) {
    u32 v = hA[b];
    if (v) atomicAdd(&gHistA[b], v);
  }
}

// ---------------- K2: cut bin for top-128 IoU ----------------
__global__ __launch_bounds__(1024) void rpn_cut(const u32* __restrict__ gHistA,
                                                u32* __restrict__ counters) {
  __shared__ u32 sh[1024];
  u32 tid = threadIdx.x;
  sh[tid] = gHistA[tid];
  __syncthreads();
  for (u32 off = 1u; off < 1024u; off <<= 1) {
    u32 v = sh[tid];
    u32 a = (tid + off < 1024u) ? sh[tid + off] : 0u;
    __syncthreads();
    sh[tid] = v + a;
    __syncthreads();
  }
  // suffix sums; cut = max b with suffix[b] >= 128 (counters[4] pre-zeroed)
  if (sh[tid] >= 128u && (tid == 1023u || sh[tid + 1] < 128u))
    atomicMax(&counters[4], tid);
}

// ---------------- K3: recompute IoU, keep >= cut ----------------
__global__ __launch_bounds__(256) void rpn_topA(
    const float4* __restrict__ props, const float4* __restrict__ gt,
    u64* __restrict__ bufTopA, u32* __restrict__ counters) {
  __shared__ float4 gtS[N_GT];
  const u32 tid = threadIdx.x;
  for (u32 j = tid; j < N_GT; j += 256u) gtS[j] = gt[j];
  __syncthreads();
  const u32 cut = counters[4];
  u32 p = blockIdx.x * 256u + tid;
  bool active = p < M_PROP;
  float4 pb = make_float4(0.f, 0.f, 0.f, 0.f);
  if (active) pb = props[p];
  float pa = (pb.z - pb.x) * (pb.w - pb.y);
  for (u32 g = 0u; g < N_GT; ++g) {
    float4 gb = gtS[g];
    float ga = (gb.z - gb.x) * (gb.w - gb.y);
    float wx = fminf(gb.z, pb.z) - fmaxf(gb.x, pb.x);
    float wy = fminf(gb.w, pb.w) - fmaxf(gb.y, pb.y);
    wx = fmaxf(wx, 0.0f); wy = fmaxf(wy, 0.0f);
    float inter = wx * wy;
    float iou = inter / (ga + pa - inter);
    u32 ib = __float_as_uint(iou);
    bool keep = active && (iou > 0.25f) && (iouBin(ib) >= cut);
    bool any;
    u32 s = wave_append_slot(&counters[3], keep, any);
    if (keep && s < TOPA_CAP) {
      u32 idx = g * M_PROP + p;
      bufTopA[s] = ((u64)ib << 25) | (u64)(0x1FFFFFFu - idx);
    }
  }
}

// ---------------- K4: rank-select + loss ----------------
// One-pass exact top-128 (desc) of nc distinct keys, nc <= 8192.
__device__ inline void rank_select(const u64* cand, u32 nc, u64* selKey) {
  const u32 tid = threadIdx.x;
  if (tid < 128u) selKey[tid] = 0ull;
  u64 k[8]; u32 r[8];
#pragma unroll
  for (int j = 0; j < 8; ++j) {
    u32 i = tid + (u32)j * 1024u;
    k[j] = (i < nc) ? cand[i] : 0ull;
    r[j] = 0u;
  }
  __syncthreads();
  for (u32 i = 0u; i < nc; ++i) {
    u64 v = cand[i];
#pragma unroll
    for (int j = 0; j < 8; ++j) r[j] += (v > k[j]) ? 1u : 0u;
  }
#pragma unroll
  for (int j = 0; j < 8; ++j) {
    u32 i = tid + (u32)j * 1024u;
    if (i < nc && r[j] < 128u) selKey[r[j]] = k[j];
  }
  __syncthreads();
}

// suffix-scan cut over a 1024-bin LDS histogram (destroys hist)
__device__ inline u32 block_sufcut(u32* hist, u32* s_tmp) {
  u32 tid = threadIdx.x;
  for (u32 off = 1u; off < 1024u; off <<= 1) {
    u32 v = hist[tid];
    u32 a = (tid + off < 1024u) ? hist[tid + off] : 0u;
    __syncthreads();
    hist[tid] = v + a;
    __syncthreads();
  }
  if (tid == 0u) *s_tmp = 0u;
  __syncthreads();
  if (hist[tid] >= 128u && (tid == 1023u || hist[tid + 1] < 128u))
    atomicMax(s_tmp, tid);
  __syncthreads();
  return *s_tmp;
}

__device__ inline u32 binB(u32 m) {  // phase-2 priority bins (window 2^17)
  return (m < BCUT) ? 0u : ((m - BCUT) >> 7);
}

__device__ inline float sl1(float d) {
  float ad = fabsf(d);
  return (ad < 1.0f) ? 0.5f * d * d : ad - 0.5f;
}

__global__ __launch_bounds__(1024) void rpn_finalize(
    const float* __restrict__ obj, const float4* __restrict__ props,
    const float4* __restrict__ gt,
    const u64* __restrict__ bufTopA,
    const u64* __restrict__ bufB, const u64* __restrict__ bufC,
    const u32* __restrict__ counters, float* __restrict__ out,
    u32 k2a, u32 k2b) {
  __shared__ u32 hist[1024];
  __shared__ u64 keyBuf[COMP_CAP];
  __shared__ u64 selKey[128];
  __shared__ u32 bestIdx[128];
  __shared__ float fred[1024];
  __shared__ u32 s_cnt, s_tmp;
  __shared__ float s_reg, s_bcep;

  const u32 tid = threadIdx.x;
  const u32 nT = counters[3] < TOPA_CAP ? counters[3] : TOPA_CAP;

  // ===== Phase 1: best_idx = top-128 of flat IoU (desc, ties idx asc) =====
  for (u32 i = tid; i < nT; i += 1024u) keyBuf[i] = bufTopA[i];
  __syncthreads();
  rank_select(keyBuf, nT, selKey);
  if (tid < 128u) {
    u64 k = selKey[tid];
    bestIdx[tid] = (k == 0ull) ? 0u : (0x1FFFFFFu - (u32)(k & 0x1FFFFFFu));
  }
  __syncthreads();

  // ===== Phase 2: positives = top-128 of [best_prio(128) ++ pos_prio] =====
  for (u32 i = tid; i < 1024u; i += 1024u) hist[i] = 0u;
  __syncthreads();
  u32 myM2 = 0u, myBin = 0u;
  if (tid < 128u) {
    myM2 = jax_bits32(k2a, k2b, tid) >> 9;
    myBin = binB(myM2);
    atomicAdd(&hist[myBin], 1u);
  }
  for (u32 sdx = 0u; sdx < SHARDS; ++sdx) {
    u32 n = counters[24u + sdx]; n = n < SHARD_CAP ? n : SHARD_CAP;
    const u64* sb = bufB + (size_t)sdx * SHARD_CAP;
    for (u32 i = tid; i < n; i += 1024u)
      atomicAdd(&hist[binB((u32)(sb[i] >> 25))], 1u);
  }
  __syncthreads();
  u32 cut = block_sufcut(hist, &s_tmp);
  if (tid == 0u) s_cnt = 0u;
  __syncthreads();
  if (tid < 128u && myBin >= cut) {
    u32 s = atomicAdd(&s_cnt, 1u);
    if (s < COMP_CAP) keyBuf[s] = ((u64)myM2 << 25) | (u64)(0x1FFFFFFu - tid);
  }
  for (u32 sdx = 0u; sdx < SHARDS; ++sdx) {
    u32 n = counters[24u + sdx]; n = n < SHARD_CAP ? n : SHARD_CAP;
    const u64* sb = bufB + (size_t)sdx * SHARD_CAP;
    for (u32 i = tid; i < n; i += 1024u) {
      u64 k = sb[i];
      if (binB((u32)(k >> 25)) >= cut) {
        u32 s = atomicAdd(&s_cnt, 1u);
        if (s < COMP_CAP) keyBuf[s] = k;
      }
    }
  }
  __syncthreads();
  u32 nc = s_cnt < COMP_CAP ? s_cnt : COMP_CAP;
  rank_select(keyBuf, nc, selKey);

  float locReg = 0.0f, locBce = 0.0f;
  if (tid < 128u) {
    u64 k = selKey[tid];
    if (k != 0ull) {
      u32 c = 0x1FFFFFFu - (u32)(k & 0x1FFFFFFu);
      u32 pair = (c < 128u) ? bestIdx[c] : (c - 128u);
      if (pair < NM) {
        u32 row = pair / M_PROP, col = pair % M_PROP;
        float4 pr = props[col];
        float4 gb = gt[row];
        locReg = sl1(pr.x - gb.x) + sl1(pr.y - gb.y) +
                 sl1(pr.z - gb.z) + sl1(pr.w - gb.w);
        float l = obj[col];
        locBce = fmaxf(l, 0.0f) - l + log1pf(expf(-fabsf(l)));
      }
    }
  }
  fred[tid] = locReg; __syncthreads();
  for (u32 off = 512u; off > 0u; off >>= 1) { if (tid < off) fred[tid] += fred[tid + off]; __syncthreads(); }
  if (tid == 0u) s_reg = fred[0];
  __syncthreads();
  fred[tid] = locBce; __syncthreads();
  for (u32 off = 512u; off > 0u; off >>= 1) { if (tid < off) fred[tid] += fred[tid + off]; __syncthreads(); }
  if (tid == 0u) s_bcep = fred[0];
  __syncthreads();

  // ===== Phase 3: negatives = top-128 of neg_prio =====
  for (u32 i = tid; i < 1024u; i += 1024u) hist[i] = 0u;
  __syncthreads();
  for (u32 sdx = 0u; sdx < SHARDS; ++sdx) {
    u32 n = counters[8u + sdx]; n = n < SHARD_CAP ? n : SHARD_CAP;
    const u64* sb = bufC + (size_t)sdx * SHARD_CAP;
    for (u32 i = tid; i < n; i += 1024u) {
      u32 m = (u32)(sb[i] >> 25);
      atomicAdd(&hist[(m & 0xFFFu) >> 2], 1u);  // m in [2^23-2^12, 2^23)
    }
  }
  __syncthreads();
  cut = block_sufcut(hist, &s_tmp);
  if (tid == 0u) s_cnt = 0u;
  __syncthreads();
  for (u32 sdx = 0u; sdx < SHARDS; ++sdx) {
    u32 n = counters[8u + sdx]; n = n < SHARD_CAP ? n : SHARD_CAP;
    const u64* sb = bufC + (size_t)sdx * SHARD_CAP;
    for (u32 i = tid; i < n; i += 1024u) {
      u64 k = sb[i];
      u32 m = (u32)(k >> 25);
      if (((m & 0xFFFu) >> 2) >= cut) {
        u32 s = atomicAdd(&s_cnt, 1u);
        if (s < COMP_CAP) keyBuf[s] = k;
      }
    }
  }
  __syncthreads();
  nc = s_cnt < COMP_CAP ? s_cnt : COMP_CAP;
  rank_select(keyBuf, nc, selKey);

  float locBceN = 0.0f;
  if (tid < 128u) {
    u64 k = selKey[tid];
    if (k != 0ull) {
      u32 idx = 0x1FFFFFFu - (u32)(k & 0x1FFFFFFu);
      u32 col = idx % M_PROP;
      float l = obj[col];
      locBceN = fmaxf(l, 0.0f) + log1pf(expf(-fabsf(l)));
    }
  }
  fred[tid] = locBceN; __syncthreads();
  for (u32 off = 512u; off > 0u; off >>= 1) { if (tid < off) fred[tid] += fred[tid + off]; __syncthreads(); }
  if (tid == 0u) {
    float cls = (s_bcep + fred[0]) / 256.0f;
    float reg = s_reg / 512.0f;
    out[0] = cls + 10.0f * reg;
  }
}

extern "C" void kernel_launch(void* const* d_in, const int* in_sizes, int n_in,
                              void* d_out, int out_size, void* d_ws, size_t ws_size,
                              hipStream_t stream) {
  (void)in_sizes; (void)n_in; (void)out_size; (void)ws_size;
  const float* obj = (const float*)d_in[0];
  const float4* props = (const float4*)d_in[1];
  const float4* gt = (const float4*)d_in[2];
  float* out = (float*)d_out;

  u32 k1a, k1b, k2a, k2b, k3a, k3b;
  jax_split3(k1a, k1b, k2a, k2b, k3a, k3b);

  // ws layout: counters(256B) | gHistA(4KB) | bufTopA(64KB) | bufB(512KB) | bufC(512KB)
  uint8_t* base = (uint8_t*)d_ws;
  u32* counters = (u32*)base;
  u32* gHistA = (u32*)(base + 256);
  u64* bufTopA = (u64*)(base + 256 + 4096);
  u64* bufB = (u64*)(base + 256 + 4096 + (size_t)TOPA_CAP * 8);
  u64* bufC = bufB + (size_t)SHARDS * SHARD_CAP;

  const u32 grid = (M_PROP + 255u) / 256u;
  rpn_init<<<1, 256, 0, stream>>>(counters, gHistA);
  rpn_collect<<<grid, 256, 0, stream>>>(props, gt, bufB, bufC, counters,
                                        gHistA, k1a, k1b, k3a, k3b);
  rpn_cut<<<1, 1024, 0, stream>>>(gHistA, counters);
  rpn_topA<<<grid, 256, 0, stream>>>(props, gt, bufTopA, counters);
  rpn_finalize<<<1, 1024, 0, stream>>>(obj, props, gt, bufTopA, bufB, bufC,
                                       counters, out, k2a, k2b);
}

// Round 6
// 191.837 us; speedup vs baseline: 11.6911x; 1.1923x over previous
//
#include <hip/hip_runtime.h>
#include <stdint.h>

// All FP must match XLA's HLO op-for-op: no mul+add contraction.
#pragma clang fp contract(off)

typedef unsigned long long u64;
typedef uint32_t u32;

#define M_PROP 200000u
#define N_GT   128u
#define NM     25600000u
#define GSPLIT 2u
#define GHALF  64u

// priority cuts (23-bit priorities):
//  B: pos pairs (iou>0.4, ~500k) with m1 >= 2^23-2^17 -> ~7.8k kept; since
//     #kept >= 128, the true top-128 pos-priority keys are all kept (exact).
//  C: neg pairs (iou<0.1, ~25.1M) with m3 >= 2^23-2^12 -> ~12.3k kept.
#define BCUT 8257536u   // 2^23 - 2^17
#define CCUT 8384512u   // 2^23 - 2^12

#define SHARDS 16u
#define SHARD_CAP 4096u
#define ACAP_SHARD 65536u
#define TOPA_CAP 8192u
#define COMP_CAP 8192u
#define BCAP 768u        // per-wave B-precandidate LDS staging (u32 idx)
#define ACAP_L 384u      // per-wave A-key LDS staging (u64 key)

// counter slots, each padded to 1KB (256 u32) to spread L2 atomic traffic:
// slot 0..15 = C shards, 16..31 = B shards, 32..47 = A shards,
// slot 48 = cntTopA, 49 = cutA
#define CSLOT(i) counters[(u32)(i) * 256u]

// ---------------- threefry2x32 (20 rounds) ----------------
__host__ __device__ inline void tf2x32(u32 k0, u32 k1, u32 x0, u32 x1,
                                       u32& o0, u32& o1) {
  u32 ks0 = k0, ks1 = k1, ks2 = k0 ^ k1 ^ 0x1BD11BDAu;
  x0 += ks0; x1 += ks1;
#define TF_R(r) { x0 += x1; x1 = (x1 << r) | (x1 >> (32 - r)); x1 ^= x0; }
  TF_R(13) TF_R(15) TF_R(26) TF_R(6)
  x0 += ks1; x1 += ks2 + 1u;
  TF_R(17) TF_R(29) TF_R(16) TF_R(24)
  x0 += ks2; x1 += ks0 + 2u;
  TF_R(13) TF_R(15) TF_R(26) TF_R(6)
  x0 += ks0; x1 += ks1 + 3u;
  TF_R(17) TF_R(29) TF_R(16) TF_R(24)
  x0 += ks1; x1 += ks2 + 4u;
  TF_R(13) TF_R(15) TF_R(26) TF_R(6)
  x0 += ks2; x1 += ks0 + 5u;
#undef TF_R
  o0 = x0; o1 = x1;
}

// partitionable threefry: 32 bits for element idx
__device__ inline u32 jax_bits32(u32 ka, u32 kb, u32 idx) {
  u32 a, b; tf2x32(ka, kb, 0u, idx, a, b);
  return a ^ b;
}

static void jax_split3(u32& k1a, u32& k1b, u32& k2a, u32& k2b,
                       u32& k3a, u32& k3b) {
  const u32 K0 = 0u, K1 = 42u;
  tf2x32(K0, K1, 0u, 0u, k1a, k1b);
  tf2x32(K0, K1, 0u, 1u, k2a, k2b);
  tf2x32(K0, K1, 0u, 2u, k3a, k3b);
}

// wave-aggregated append (one atomic per wave per predicate)
__device__ inline u32 wave_append_slot(u32* ctr, bool pred, bool& any) {
  u64 mask = __ballot(pred);
  if (mask == 0ull) { any = false; return 0u; }
  any = true;
  u32 lane = threadIdx.x & 63u;
  u32 prefix = (u32)__popcll(mask & ((1ull << lane) - 1ull));
  int leader = __ffsll(mask) - 1;
  u32 base = 0u;
  if ((int)lane == leader) base = atomicAdd(ctr, (u32)__popcll(mask));
  base = __shfl(base, leader, 64);
  return base + prefix;
}

// two predicates, one atomic (order within buffer irrelevant)
__device__ inline void wave_append2(u32* ctr, u64* buf, u32 cap,
                                    bool p0, u64 v0, bool p1, u64 v1) {
  u64 m0 = __ballot(p0);
  u64 m1 = __ballot(p1);
  if ((m0 | m1) == 0ull) return;
  u32 lane = threadIdx.x & 63u;
  u64 laneLT = (1ull << lane) - 1ull;
  u32 n0 = (u32)__popcll(m0);
  u32 tot = n0 + (u32)__popcll(m1);
  int leader = __ffsll(m0 | m1) - 1;
  u32 base = 0u;
  if ((int)lane == leader) base = atomicAdd(ctr, tot);
  base = __shfl(base, leader, 64);
  if (p0) { u32 s = base + (u32)__popcll(m0 & laneLT); if (s < cap) buf[s] = v0; }
  if (p1) { u32 s = base + n0 + (u32)__popcll(m1 & laneLT); if (s < cap) buf[s] = v1; }
}

__device__ inline u32 iouBin(u32 bits) {  // monotone bins over (0.25, 1.0]
  u32 b = (bits - 0x3E800000u) >> 14;
  return b > 1023u ? 1023u : b;
}

// ---------------- K0: zero counters + global histogram ----------------
__global__ __launch_bounds__(256) void rpn_init(u32* counters, u32* gHistA) {
  u32 tid = threadIdx.x;
  if (tid < 64u) CSLOT(tid) = 0u;
  for (u32 i = tid; i < 1024u; i += 256u) gHistA[i] = 0u;
}

// ---------------- K1: IoU + hist + A/B/C candidate collection ----------------
__global__ __launch_bounds__(256) void rpn_collect(
    const float4* __restrict__ props, const float4* __restrict__ gt,
    u64* __restrict__ bufA, u64* __restrict__ bufB, u64* __restrict__ bufC,
    u32* __restrict__ counters, u32* __restrict__ gHistA,
    u32 k1a, u32 k1b, u32 k3a, u32 k3b) {
  __shared__ float4 gtS[GHALF];
  __shared__ u32 hA[1024];
  __shared__ u32 listB[4][BCAP];
  __shared__ u64 listA[4][ACAP_L];
  const u32 tid = threadIdx.x;
  const u32 lane = tid & 63u;
  const u32 wid = tid >> 6;
  const u32 gbase = blockIdx.y * GHALF;
  for (u32 i = tid; i < 1024u; i += 256u) hA[i] = 0u;
  for (u32 j = tid; j < GHALF; j += 256u) gtS[j] = gt[gbase + j];
  __syncthreads();

  const u32 shard = (blockIdx.x * GSPLIT + blockIdx.y) & (SHARDS - 1u);
  u32* cntC_g = &CSLOT(shard);
  u32* cntB_g = &CSLOT(16u + shard);
  u32* cntA_g = &CSLOT(32u + shard);
  u64* myBufC = bufC + (size_t)shard * SHARD_CAP;
  u64* myBufB = bufB + (size_t)shard * SHARD_CAP;
  u64* myBufA = bufA + (size_t)shard * ACAP_SHARD;

  u32 p = blockIdx.x * 256u + tid;
  bool active = p < M_PROP;
  float4 pb = make_float4(0.f, 0.f, 0.f, 0.f);
  if (active) pb = props[p];
  float pa = (pb.z - pb.x) * (pb.w - pb.y);

  u32 cntB = 0u, cntA = 0u;  // wave-uniform (derived from ballots only)
  const u64 laneLT = (1ull << lane) - 1ull;

#define PROCESS_B()                                                          \
  {                                                                          \
    for (u32 i = lane; i < cntB; i += 64u) {                                 \
      u32 bidx = listB[wid][i];                                              \
      u32 m1 = jax_bits32(k1a, k1b, bidx) >> 9;                              \
      bool keep = m1 >= BCUT;                                                \
      bool anyk;                                                             \
      u32 sk = wave_append_slot(cntB_g, keep, anyk);                         \
      if (keep && sk < SHARD_CAP)                                            \
        myBufB[sk] = ((u64)m1 << 25) | (u64)(0x1FFFFFFu - (bidx + 128u));    \
    }                                                                        \
    cntB = 0u;                                                               \
  }

#define PROCESS_A()                                                          \
  {                                                                          \
    for (u32 i = lane; i < cntA; i += 64u) {                                 \
      u64 kv = listA[wid][i];                                                \
      bool anyk;                                                             \
      u32 sk = wave_append_slot(cntA_g, true, anyk);                         \
      if (sk < ACAP_SHARD) myBufA[sk] = kv;                                  \
    }                                                                        \
    cntA = 0u;                                                               \
  }

  for (u32 gg = 0u; gg < GHALF; gg += 2u) {
    float4 g0 = gtS[gg];
    float4 g1 = gtS[gg + 1u];
    float ga0 = (g0.z - g0.x) * (g0.w - g0.y);
    float wx0 = fminf(g0.z, pb.z) - fmaxf(g0.x, pb.x);
    float wy0 = fminf(g0.w, pb.w) - fmaxf(g0.y, pb.y);
    wx0 = fmaxf(wx0, 0.0f); wy0 = fmaxf(wy0, 0.0f);
    float in0 = wx0 * wy0;
    float iou0 = in0 / (ga0 + pa - in0);
    float ga1 = (g1.z - g1.x) * (g1.w - g1.y);
    float wx1 = fminf(g1.z, pb.z) - fmaxf(g1.x, pb.x);
    float wy1 = fminf(g1.w, pb.w) - fmaxf(g1.y, pb.y);
    wx1 = fmaxf(wx1, 0.0f); wy1 = fmaxf(wy1, 0.0f);
    float in1 = wx1 * wy1;
    float iou1 = in1 / (ga1 + pa - in1);
    u32 idx0 = (gbase + gg) * M_PROP + p;
    u32 idx1 = idx0 + M_PROP;
    u32 ib0 = __float_as_uint(iou0);
    u32 ib1 = __float_as_uint(iou1);

    // two independent threefry chains, unconditional (98% needed anyway)
    u32 m30 = jax_bits32(k3a, k3b, idx0) >> 9;
    u32 m31 = jax_bits32(k3a, k3b, idx1) >> 9;

    // A: histogram + stage key into per-wave LDS list
    bool a0 = active && (iou0 > 0.25f);
    bool a1 = active && (iou1 > 0.25f);
    if (a0) atomicAdd(&hA[iouBin(ib0)], 1u);
    if (a1) atomicAdd(&hA[iouBin(ib1)], 1u);
    u64 ma0 = __ballot(a0);
    if (ma0) {
      u32 pfx = (u32)__popcll(ma0 & laneLT);
      if (a0) listA[wid][cntA + pfx] = ((u64)ib0 << 25) | (u64)(0x1FFFFFFu - idx0);
      cntA += (u32)__popcll(ma0);
    }
    u64 ma1 = __ballot(a1);
    if (ma1) {
      u32 pfx = (u32)__popcll(ma1 & laneLT);
      if (a1) listA[wid][cntA + pfx] = ((u64)ib1 << 25) | (u64)(0x1FFFFFFu - idx1);
      cntA += (u32)__popcll(ma1);
    }

    // C: direct sharded global append (fused two-predicate, one atomic)
    bool c0 = active && (iou0 < 0.1f) && (m30 >= CCUT);
    bool c1 = active && (iou1 < 0.1f) && (m31 >= CCUT);
    wave_append2(cntC_g, myBufC, SHARD_CAP, c0,
                 ((u64)m30 << 25) | (u64)(0x1FFFFFFu - idx0), c1,
                 ((u64)m31 << 25) | (u64)(0x1FFFFFFu - idx1));

    // B: stage idx into per-wave LDS list (dense threefry later)
    bool b0 = active && (iou0 > 0.4f);
    u64 mb0 = __ballot(b0);
    if (mb0) {
      u32 pfx = (u32)__popcll(mb0 & laneLT);
      if (b0) listB[wid][cntB + pfx] = idx0;
      cntB += (u32)__popcll(mb0);
    }
    bool b1 = active && (iou1 > 0.4f);
    u64 mb1 = __ballot(b1);
    if (mb1) {
      u32 pfx = (u32)__popcll(mb1 & laneLT);
      if (b1) listB[wid][cntB + pfx] = idx1;
      cntB += (u32)__popcll(mb1);
    }
    if (cntB > BCAP - 128u) PROCESS_B();
    if (cntA > ACAP_L - 128u) PROCESS_A();
  }
  PROCESS_B();
  PROCESS_A();
#undef PROCESS_B
#undef PROCESS_A

  __syncthreads();
  for (u32 b = tid; b < 1024u; b += 256u) {
    u32 v = hA[b];
    if (v) atomicAdd(&gHistA[b], v);
  }
}

// ---------------- K2: cut bin for top-128 IoU ----------------
__global__ __launch_bounds__(1024) void rpn_cut(const u32* __restrict__ gHistA,
                                                u32* __restrict__ counters) {
  __shared__ u32 sh[1024];
  u32 tid = threadIdx.x;
  sh[tid] = gHistA[tid];
  __syncthreads();
  for (u32 off = 1u; off < 1024u; off <<= 1) {
    u32 v = sh[tid];
    u32 a = (tid + off < 1024u) ? sh[tid + off] : 0u;
    __syncthreads();
    sh[tid] = v + a;
    __syncthreads();
  }
  // suffix sums; cut = max b with suffix[b] >= 128 (slot 49 pre-zeroed)
  if (sh[tid] >= 128u && (tid == 1023u || sh[tid + 1] < 128u))
    atomicMax(&CSLOT(49), tid);
}

// ---------------- K3: filter stored A-keys by cut ----------------
__global__ __launch_bounds__(256) void rpn_filterA(
    const u64* __restrict__ bufA, u32* __restrict__ counters,
    u64* __restrict__ bufTopA) {
  const u32 cut = CSLOT(49);
  const u32 tid = threadIdx.x;
  for (u32 sh = 0u; sh < SHARDS; ++sh) {
    u32 n = CSLOT(32u + sh); n = n < ACAP_SHARD ? n : ACAP_SHARD;
    const u64* sb = bufA + (size_t)sh * ACAP_SHARD;
    for (u32 i = blockIdx.x * 256u + tid; i < n; i += gridDim.x * 256u) {
      u64 k = sb[i];
      bool keep = iouBin((u32)(k >> 25)) >= cut;
      bool any;
      u32 s = wave_append_slot(&CSLOT(48), keep, any);
      if (keep && s < TOPA_CAP) bufTopA[s] = k;
    }
  }
}

// ---------------- K4: rank-select + loss ----------------
// One-pass exact top-128 (desc) of nc distinct keys, nc <= 8192.
__device__ inline void rank_select(const u64* cand, u32 nc, u64* selKey) {
  const u32 tid = threadIdx.x;
  if (tid < 128u) selKey[tid] = 0ull;
  u64 k[8]; u32 r[8];
#pragma unroll
  for (int j = 0; j < 8; ++j) {
    u32 i = tid + (u32)j * 1024u;
    k[j] = (i < nc) ? cand[i] : 0ull;
    r[j] = 0u;
  }
  __syncthreads();
  for (u32 i = 0u; i < nc; ++i) {
    u64 v = cand[i];
#pragma unroll
    for (int j = 0; j < 8; ++j) r[j] += (v > k[j]) ? 1u : 0u;
  }
#pragma unroll
  for (int j = 0; j < 8; ++j) {
    u32 i = tid + (u32)j * 1024u;
    if (i < nc && r[j] < 128u) selKey[r[j]] = k[j];
  }
  __syncthreads();
}

// suffix-scan cut over a 1024-bin LDS histogram (destroys hist)
__device__ inline u32 block_sufcut(u32* hist, u32* s_tmp) {
  u32 tid = threadIdx.x;
  for (u32 off = 1u; off < 1024u; off <<= 1) {
    u32 v = hist[tid];
    u32 a = (tid + off < 1024u) ? hist[tid + off] : 0u;
    __syncthreads();
    hist[tid] = v + a;
    __syncthreads();
  }
  if (tid == 0u) *s_tmp = 0u;
  __syncthreads();
  if (hist[tid] >= 128u && (tid == 1023u || hist[tid + 1] < 128u))
    atomicMax(s_tmp, tid);
  __syncthreads();
  return *s_tmp;
}

__device__ inline u32 binB(u32 m) {  // phase-2 priority bins (window 2^17)
  return (m < BCUT) ? 0u : ((m - BCUT) >> 7);
}

__device__ inline float sl1(float d) {
  float ad = fabsf(d);
  return (ad < 1.0f) ? 0.5f * d * d : ad - 0.5f;
}

__global__ __launch_bounds__(1024) void rpn_finalize(
    const float* __restrict__ obj, const float4* __restrict__ props,
    const float4* __restrict__ gt,
    const u64* __restrict__ bufTopA,
    const u64* __restrict__ bufB, const u64* __restrict__ bufC,
    const u32* __restrict__ counters, float* __restrict__ out,
    u32 k2a, u32 k2b) {
  __shared__ u32 hist[1024];
  __shared__ u64 keyBuf[COMP_CAP];
  __shared__ u64 selKey[128];
  __shared__ u32 bestIdx[128];
  __shared__ float fred[1024];
  __shared__ u32 s_cnt, s_tmp;
  __shared__ float s_reg, s_bcep;

  const u32 tid = threadIdx.x;
  u32 nT = CSLOT(48); nT = nT < TOPA_CAP ? nT : TOPA_CAP;

  // ===== Phase 1: best_idx = top-128 of flat IoU (desc, ties idx asc) =====
  for (u32 i = tid; i < nT; i += 1024u) keyBuf[i] = bufTopA[i];
  __syncthreads();
  rank_select(keyBuf, nT, selKey);
  if (tid < 128u) {
    u64 k = selKey[tid];
    bestIdx[tid] = (k == 0ull) ? 0u : (0x1FFFFFFu - (u32)(k & 0x1FFFFFFu));
  }
  __syncthreads();

  // ===== Phase 2: positives = top-128 of [best_prio(128) ++ pos_prio] =====
  for (u32 i = tid; i < 1024u; i += 1024u) hist[i] = 0u;
  __syncthreads();
  u32 myM2 = 0u, myBin = 0u;
  if (tid < 128u) {
    myM2 = jax_bits32(k2a, k2b, tid) >> 9;
    myBin = binB(myM2);
    atomicAdd(&hist[myBin], 1u);
  }
  for (u32 sdx = 0u; sdx < SHARDS; ++sdx) {
    u32 n = CSLOT(16u + sdx); n = n < SHARD_CAP ? n : SHARD_CAP;
    const u64* sb = bufB + (size_t)sdx * SHARD_CAP;
    for (u32 i = tid; i < n; i += 1024u)
      atomicAdd(&hist[binB((u32)(sb[i] >> 25))], 1u);
  }
  __syncthreads();
  u32 cut = block_sufcut(hist, &s_tmp);
  if (tid == 0u) s_cnt = 0u;
  __syncthreads();
  if (tid < 128u && myBin >= cut) {
    u32 s = atomicAdd(&s_cnt, 1u);
    if (s < COMP_CAP) keyBuf[s] = ((u64)myM2 << 25) | (u64)(0x1FFFFFFu - tid);
  }
  for (u32 sdx = 0u; sdx < SHARDS; ++sdx) {
    u32 n = CSLOT(16u + sdx); n = n < SHARD_CAP ? n : SHARD_CAP;
    const u64* sb = bufB + (size_t)sdx * SHARD_CAP;
    for (u32 i = tid; i < n; i += 1024u) {
      u64 k = sb[i];
      if (binB((u32)(k >> 25)) >= cut) {
        u32 s = atomicAdd(&s_cnt, 1u);
        if (s < COMP_CAP) keyBuf[s] = k;
      }
    }
  }
  __syncthreads();
  u32 nc = s_cnt < COMP_CAP ? s_cnt : COMP_CAP;
  rank_select(keyBuf, nc, selKey);

  float locReg = 0.0f, locBce = 0.0f;
  if (tid < 128u) {
    u64 k = selKey[tid];
    if (k != 0ull) {
      u32 c = 0x1FFFFFFu - (u32)(k & 0x1FFFFFFu);
      u32 pair = (c < 128u) ? bestIdx[c] : (c - 128u);
      if (pair < NM) {
        u32 row = pair / M_PROP, col = pair % M_PROP;
        float4 pr = props[col];
        float4 gb = gt[row];
        locReg = sl1(pr.x - gb.x) + sl1(pr.y - gb.y) +
                 sl1(pr.z - gb.z) + sl1(pr.w - gb.w);
        float l = obj[col];
        locBce = fmaxf(l, 0.0f) - l + log1pf(expf(-fabsf(l)));
      }
    }
  }
  fred[tid] = locReg; __syncthreads();
  for (u32 off = 512u; off > 0u; off >>= 1) { if (tid < off) fred[tid] += fred[tid + off]; __syncthreads(); }
  if (tid == 0u) s_reg = fred[0];
  __syncthreads();
  fred[tid] = locBce; __syncthreads();
  for (u32 off = 512u; off > 0u; off >>= 1) { if (tid < off) fred[tid] += fred[tid + off]; __syncthreads(); }
  if (tid == 0u) s_bcep = fred[0];
  __syncthreads();

  // ===== Phase 3: negatives = top-128 of neg_prio =====
  for (u32 i = tid; i < 1024u; i += 1024u) hist[i] = 0u;
  __syncthreads();
  for (u32 sdx = 0u; sdx < SHARDS; ++sdx) {
    u32 n = CSLOT(sdx); n = n < SHARD_CAP ? n : SHARD_CAP;
    const u64* sb = bufC + (size_t)sdx * SHARD_CAP;
    for (u32 i = tid; i < n; i += 1024u) {
      u32 m = (u32)(sb[i] >> 25);
      atomicAdd(&hist[(m & 0xFFFu) >> 2], 1u);  // m in [2^23-2^12, 2^23)
    }
  }
  __syncthreads();
  cut = block_sufcut(hist, &s_tmp);
  if (tid == 0u) s_cnt = 0u;
  __syncthreads();
  for (u32 sdx = 0u; sdx < SHARDS; ++sdx) {
    u32 n = CSLOT(sdx); n = n < SHARD_CAP ? n : SHARD_CAP;
    const u64* sb = bufC + (size_t)sdx * SHARD_CAP;
    for (u32 i = tid; i < n; i += 1024u) {
      u64 k = sb[i];
      u32 m = (u32)(k >> 25);
      if (((m & 0xFFFu) >> 2) >= cut) {
        u32 s = atomicAdd(&s_cnt, 1u);
        if (s < COMP_CAP) keyBuf[s] = k;
      }
    }
  }
  __syncthreads();
  nc = s_cnt < COMP_CAP ? s_cnt : COMP_CAP;
  rank_select(keyBuf, nc, selKey);

  float locBceN = 0.0f;
  if (tid < 128u) {
    u64 k = selKey[tid];
    if (k != 0ull) {
      u32 idx = 0x1FFFFFFu - (u32)(k & 0x1FFFFFFu);
      u32 col = idx % M_PROP;
      float l = obj[col];
      locBceN = fmaxf(l, 0.0f) + log1pf(expf(-fabsf(l)));
    }
  }
  fred[tid] = locBceN; __syncthreads();
  for (u32 off = 512u; off > 0u; off >>= 1) { if (tid < off) fred[tid] += fred[tid + off]; __syncthreads(); }
  if (tid == 0u) {
    float cls = (s_bcep + fred[0]) / 256.0f;
    float reg = s_reg / 512.0f;
    out[0] = cls + 10.0f * reg;
  }
}

extern "C" void kernel_launch(void* const* d_in, const int* in_sizes, int n_in,
                              void* d_out, int out_size, void* d_ws, size_t ws_size,
                              hipStream_t stream) {
  (void)in_sizes; (void)n_in; (void)out_size; (void)ws_size;
  const float* obj = (const float*)d_in[0];
  const float4* props = (const float4*)d_in[1];
  const float4* gt = (const float4*)d_in[2];
  float* out = (float*)d_out;

  u32 k1a, k1b, k2a, k2b, k3a, k3b;
  jax_split3(k1a, k1b, k2a, k2b, k3a, k3b);

  // ws layout: counters(64KB padded slots) | gHistA(4KB) | bufTopA(64KB)
  //            | bufB(512KB) | bufC(512KB) | bufA(8MB)
  uint8_t* base = (uint8_t*)d_ws;
  u32* counters = (u32*)base;
  u32* gHistA = (u32*)(base + 65536);
  u64* bufTopA = (u64*)(base + 65536 + 4096);
  u64* bufB = (u64*)(base + 65536 + 4096 + (size_t)TOPA_CAP * 8);
  u64* bufC = bufB + (size_t)SHARDS * SHARD_CAP;
  u64* bufA = bufC + (size_t)SHARDS * SHARD_CAP;

  const u32 gridX = (M_PROP + 255u) / 256u;
  rpn_init<<<1, 256, 0, stream>>>(counters, gHistA);
  rpn_collect<<<dim3(gridX, GSPLIT), 256, 0, stream>>>(
      props, gt, bufA, bufB, bufC, counters, gHistA, k1a, k1b, k3a, k3b);
  rpn_cut<<<1, 1024, 0, stream>>>(gHistA, counters);
  rpn_filterA<<<64, 256, 0, stream>>>(bufA, counters, bufTopA);
  rpn_finalize<<<1, 1024, 0, stream>>>(obj, props, gt, bufTopA, bufB, bufC,
                                       counters, out, k2a, k2b);
}

// Round 7
// 140.546 us; speedup vs baseline: 15.9577x; 1.3649x over previous
//
#include <hip/hip_runtime.h>
#include <stdint.h>

// All FP must match XLA's HLO op-for-op: no mul+add contraction.
#pragma clang fp contract(off)

typedef unsigned long long u64;
typedef uint32_t u32;

#define M_PROP 200000u
#define N_GT   128u
#define NM     25600000u
#define GSPLIT 4u
#define GPART  32u

// priority keep-windows (23-bit priorities), sized so finalize can use a
// 64-bin cut and candidates fit LDS:
//  B: pos pairs (iou>0.4, ~500k) with m1 >= 2^23-2^15 -> E~1953 kept (41sigma
//     above 128) ==> top-128 pos keys all kept (exact; any dropped key is
//     below >=1953 kept keys).
//  C: neg pairs (iou<0.1, ~25.1M) with m3 >= 2^23-2^10 -> E~3065 kept.
#define BCUT 8355840u   // 2^23 - 2^15
#define CCUT 8387584u   // 2^23 - 1024

#define SHARDS 16u
#define SHARD_CAP 4096u
#define ACAP_SHARD 65536u
#define TOPA_CAP 8192u
#define COMP_CAP 8192u
#define BCAP 512u        // per-wave B-precandidate LDS staging (u32 idx)
#define ACAP_L 512u      // per-wave A-key LDS staging (u64 key)

// counter slots, each padded to 1KB to spread L2 atomic traffic:
// 0..15 = C shards, 16..31 = B shards, 32..47 = A shards, 48 = cntTopA
#define CSLOT(i) counters[(u32)(i) * 256u]

// ---------------- threefry2x32 (20 rounds) ----------------
__host__ __device__ inline void tf2x32(u32 k0, u32 k1, u32 x0, u32 x1,
                                       u32& o0, u32& o1) {
  u32 ks0 = k0, ks1 = k1, ks2 = k0 ^ k1 ^ 0x1BD11BDAu;
  x0 += ks0; x1 += ks1;
#define TF_R(r) { x0 += x1; x1 = (x1 << r) | (x1 >> (32 - r)); x1 ^= x0; }
  TF_R(13) TF_R(15) TF_R(26) TF_R(6)
  x0 += ks1; x1 += ks2 + 1u;
  TF_R(17) TF_R(29) TF_R(16) TF_R(24)
  x0 += ks2; x1 += ks0 + 2u;
  TF_R(13) TF_R(15) TF_R(26) TF_R(6)
  x0 += ks0; x1 += ks1 + 3u;
  TF_R(17) TF_R(29) TF_R(16) TF_R(24)
  x0 += ks1; x1 += ks2 + 4u;
  TF_R(13) TF_R(15) TF_R(26) TF_R(6)
  x0 += ks2; x1 += ks0 + 5u;
#undef TF_R
  o0 = x0; o1 = x1;
}

// partitionable threefry: 32 bits for element idx
__device__ inline u32 jax_bits32(u32 ka, u32 kb, u32 idx) {
  u32 a, b; tf2x32(ka, kb, 0u, idx, a, b);
  return a ^ b;
}

static void jax_split3(u32& k1a, u32& k1b, u32& k2a, u32& k2b,
                       u32& k3a, u32& k3b) {
  const u32 K0 = 0u, K1 = 42u;
  tf2x32(K0, K1, 0u, 0u, k1a, k1b);
  tf2x32(K0, K1, 0u, 1u, k2a, k2b);
  tf2x32(K0, K1, 0u, 2u, k3a, k3b);
}

// wave-aggregated append (one atomic per wave per predicate)
__device__ inline u32 wave_append_slot(u32* ctr, bool pred, bool& any) {
  u64 mask = __ballot(pred);
  if (mask == 0ull) { any = false; return 0u; }
  any = true;
  u32 lane = threadIdx.x & 63u;
  u32 prefix = (u32)__popcll(mask & ((1ull << lane) - 1ull));
  int leader = __ffsll(mask) - 1;
  u32 base = 0u;
  if ((int)lane == leader) base = atomicAdd(ctr, (u32)__popcll(mask));
  base = __shfl(base, leader, 64);
  return base + prefix;
}

// four predicates, one atomic (order within buffer irrelevant)
__device__ inline void wave_append4(u32* ctr, u64* buf, u32 cap,
                                    const bool* p, const u64* v) {
  u64 m0 = __ballot(p[0]);
  u64 m1 = __ballot(p[1]);
  u64 m2 = __ballot(p[2]);
  u64 m3 = __ballot(p[3]);
  if ((m0 | m1 | m2 | m3) == 0ull) return;
  u32 lane = threadIdx.x & 63u;
  u64 laneLT = (1ull << lane) - 1ull;
  u32 n0 = (u32)__popcll(m0), n1 = (u32)__popcll(m1);
  u32 n2 = (u32)__popcll(m2), n3 = (u32)__popcll(m3);
  int leader = __ffsll(m0 | m1 | m2 | m3) - 1;
  u32 base = 0u;
  if ((int)lane == leader) base = atomicAdd(ctr, n0 + n1 + n2 + n3);
  base = __shfl(base, leader, 64);
  if (p[0]) { u32 s = base + (u32)__popcll(m0 & laneLT); if (s < cap) buf[s] = v[0]; }
  base += n0;
  if (p[1]) { u32 s = base + (u32)__popcll(m1 & laneLT); if (s < cap) buf[s] = v[1]; }
  base += n1;
  if (p[2]) { u32 s = base + (u32)__popcll(m2 & laneLT); if (s < cap) buf[s] = v[2]; }
  base += n2;
  if (p[3]) { u32 s = base + (u32)__popcll(m3 & laneLT); if (s < cap) buf[s] = v[3]; }
}

__device__ inline u32 iouBin(u32 bits) {  // monotone bins over (0.25, 1.0]
  u32 b = (bits - 0x3E800000u) >> 14;
  return b > 1023u ? 1023u : b;
}

// ---------------- K0: zero counters + global histogram ----------------
__global__ __launch_bounds__(256) void rpn_init(u32* counters, u32* gHistA) {
  u32 tid = threadIdx.x;
  if (tid < 64u) CSLOT(tid) = 0u;
  for (u32 i = tid; i < 1024u; i += 256u) gHistA[i] = 0u;
}

// ---------------- K1: IoU + hist + A/B/C candidate collection ----------------
__global__ __launch_bounds__(256) void rpn_collect(
    const float4* __restrict__ props, const float4* __restrict__ gt,
    u64* __restrict__ bufA, u64* __restrict__ bufB, u64* __restrict__ bufC,
    u32* __restrict__ counters, u32* __restrict__ gHistA,
    u32 k1a, u32 k1b, u32 k3a, u32 k3b) {
  __shared__ float4 gtS[GPART];
  __shared__ float gtAreaS[GPART];
  __shared__ u32 hA[1024];
  __shared__ u32 listB[4][BCAP];
  __shared__ u64 listA[4][ACAP_L];
  const u32 tid = threadIdx.x;
  const u32 lane = tid & 63u;
  const u32 wid = tid >> 6;
  const u32 gbase = blockIdx.y * GPART;
  for (u32 i = tid; i < 1024u; i += 256u) hA[i] = 0u;
  for (u32 j = tid; j < GPART; j += 256u) {
    float4 gb = gt[gbase + j];
    gtS[j] = gb;
    gtAreaS[j] = (gb.z - gb.x) * (gb.w - gb.y);
  }
  __syncthreads();

  const u32 shard = (blockIdx.x * GSPLIT + blockIdx.y) & (SHARDS - 1u);
  u32* cntC_g = &CSLOT(shard);
  u32* cntB_g = &CSLOT(16u + shard);
  u32* cntA_g = &CSLOT(32u + shard);
  u64* myBufC = bufC + (size_t)shard * SHARD_CAP;
  u64* myBufB = bufB + (size_t)shard * SHARD_CAP;
  u64* myBufA = bufA + (size_t)shard * ACAP_SHARD;

  u32 p = blockIdx.x * 256u + tid;
  bool active = p < M_PROP;
  float4 pb = make_float4(0.f, 0.f, 0.f, 0.f);
  if (active) pb = props[p];
  float pa = (pb.z - pb.x) * (pb.w - pb.y);

  u32 cntB = 0u, cntA = 0u;  // wave-uniform (derived from ballots only)
  const u64 laneLT = (1ull << lane) - 1ull;

#define PROCESS_B()                                                          \
  {                                                                          \
    for (u32 i = lane; i < cntB; i += 64u) {                                 \
      u32 bidx = listB[wid][i];                                              \
      u32 m1 = jax_bits32(k1a, k1b, bidx) >> 9;                              \
      bool keep = m1 >= BCUT;                                                \
      bool anyk;                                                             \
      u32 sk = wave_append_slot(cntB_g, keep, anyk);                         \
      if (keep && sk < SHARD_CAP)                                            \
        myBufB[sk] = ((u64)m1 << 25) | (u64)(0x1FFFFFFu - (bidx + 128u));    \
    }                                                                        \
    cntB = 0u;                                                               \
  }

#define PROCESS_A()                                                          \
  {                                                                          \
    for (u32 i = lane; i < cntA; i += 64u) {                                 \
      u64 kv = listA[wid][i];                                                \
      bool anyk;                                                             \
      u32 sk = wave_append_slot(cntA_g, true, anyk);                         \
      if (sk < ACAP_SHARD) myBufA[sk] = kv;                                  \
    }                                                                        \
    cntA = 0u;                                                               \
  }

  for (u32 gg = 0u; gg < GPART; gg += 4u) {
    float iou[4]; u32 ib[4], idx[4], m3[4];
    bool aa[4], bb[4], cc[4];
    u64 cv[4];
#pragma unroll
    for (u32 r = 0u; r < 4u; ++r) {
      float4 gb = gtS[gg + r];
      float ga = gtAreaS[gg + r];
      float wx = fminf(gb.z, pb.z) - fmaxf(gb.x, pb.x);
      float wy = fminf(gb.w, pb.w) - fmaxf(gb.y, pb.y);
      wx = fmaxf(wx, 0.0f); wy = fmaxf(wy, 0.0f);
      float inter = wx * wy;
      iou[r] = inter / (ga + pa - inter);
      ib[r] = __float_as_uint(iou[r]);
      idx[r] = (gbase + gg + r) * M_PROP + p;
      m3[r] = jax_bits32(k3a, k3b, idx[r]) >> 9;  // 4 independent chains
      aa[r] = active && (iou[r] > 0.25f);
      bb[r] = active && (iou[r] > 0.4f);
      cc[r] = active && (iou[r] < 0.1f) && (m3[r] >= CCUT);
      cv[r] = ((u64)m3[r] << 25) | (u64)(0x1FFFFFFu - idx[r]);
      if (aa[r]) atomicAdd(&hA[iouBin(ib[r])], 1u);
    }
#pragma unroll
    for (u32 r = 0u; r < 4u; ++r) {
      u64 ma = __ballot(aa[r]);
      if (ma) {
        u32 pfx = (u32)__popcll(ma & laneLT);
        if (aa[r])
          listA[wid][cntA + pfx] = ((u64)ib[r] << 25) | (u64)(0x1FFFFFFu - idx[r]);
        cntA += (u32)__popcll(ma);
      }
      u64 mb = __ballot(bb[r]);
      if (mb) {
        u32 pfx = (u32)__popcll(mb & laneLT);
        if (bb[r]) listB[wid][cntB + pfx] = idx[r];
        cntB += (u32)__popcll(mb);
      }
    }
    wave_append4(cntC_g, myBufC, SHARD_CAP, cc, cv);
    if (cntB > BCAP - 256u) PROCESS_B();
    if (cntA > ACAP_L - 256u) PROCESS_A();
  }
  PROCESS_B();
  PROCESS_A();
#undef PROCESS_B
#undef PROCESS_A

  __syncthreads();
  for (u32 b = tid; b < 1024u; b += 256u) {
    u32 v = hA[b];
    if (v) atomicAdd(&gHistA[b], v);
  }
}

// ---------------- K2: per-wave shfl cut + filter stored A-keys ----------------
__global__ __launch_bounds__(256) void rpn_filterA(
    const u64* __restrict__ bufA, const u32* __restrict__ gHistA,
    u32* __restrict__ counters, u64* __restrict__ bufTopA) {
  const u32 tid = threadIdx.x;
  const u32 lane = tid & 63u;
  // each wave redundantly computes cut = max b with suffix(hist[b..]) >= 128
  u32 loc[16]; u32 t = 0u;
  const u32 bbase = lane * 16u;
#pragma unroll
  for (u32 j = 0u; j < 16u; ++j) { loc[j] = gHistA[bbase + j]; t += loc[j]; }
  u32 suf = t;
  for (u32 off = 1u; off < 64u; off <<= 1u) {
    u32 o = __shfl_down(suf, off, 64);
    if (lane + off < 64u) suf += o;
  }
  u32 cum = suf - t;   // sum over lanes > this one
  u32 cand = 0u; bool found = false;
#pragma unroll
  for (int j = 15; j >= 0; --j) {
    cum += loc[j];
    if (!found && cum >= 128u) { cand = bbase + (u32)j; found = true; }
  }
  for (u32 off = 1u; off < 64u; off <<= 1u) {
    u32 o = __shfl_xor(cand, off, 64);
    cand = o > cand ? o : cand;
  }
  const u32 cut = cand;
  for (u32 sh = 0u; sh < SHARDS; ++sh) {
    u32 n = CSLOT(32u + sh); n = n < ACAP_SHARD ? n : ACAP_SHARD;
    const u64* sb = bufA + (size_t)sh * ACAP_SHARD;
    for (u32 i = blockIdx.x * 256u + tid; i < n; i += gridDim.x * 256u) {
      u64 k = sb[i];
      bool keep = iouBin((u32)(k >> 25)) >= cut;
      bool any;
      u32 s = wave_append_slot(&CSLOT(48), keep, any);
      if (keep && s < TOPA_CAP) bufTopA[s] = k;
    }
  }
}

// ---------------- K3: rank-select + loss ----------------
// 8-slot exact top-128 (desc) of nc distinct keys, nc <= 8192.
__device__ inline void rank_select(const u64* cand, u32 nc, u64* selKey) {
  const u32 tid = threadIdx.x;
  if (tid < 128u) selKey[tid] = 0ull;
  u64 k[8]; u32 r[8];
#pragma unroll
  for (int j = 0; j < 8; ++j) {
    u32 i = tid + (u32)j * 1024u;
    k[j] = (i < nc) ? cand[i] : 0ull;
    r[j] = 0u;
  }
  __syncthreads();
  for (u32 i = 0u; i < nc; ++i) {
    u64 v = cand[i];
#pragma unroll
    for (int j = 0; j < 8; ++j) r[j] += (v > k[j]) ? 1u : 0u;
  }
#pragma unroll
  for (int j = 0; j < 8; ++j) {
    u32 i = tid + (u32)j * 1024u;
    if (i < nc && r[j] < 128u) selKey[r[j]] = k[j];
  }
  __syncthreads();
}

// 1-slot exact top-128 of nc distinct keys, nc <= 1024.
__device__ inline void rank_select2(const u64* cand, u32 nc, u64* selKey) {
  const u32 tid = threadIdx.x;
  if (tid < 128u) selKey[tid] = 0ull;
  u64 mine = (tid < nc) ? cand[tid] : 0ull;
  __syncthreads();
  u32 r = 0u;
  for (u32 i = 0u; i < nc; ++i) r += (cand[i] > mine) ? 1u : 0u;
  if (tid < nc && r < 128u) selKey[r] = mine;
  __syncthreads();
}

__device__ inline float sl1(float d) {
  float ad = fabsf(d);
  return (ad < 1.0f) ? 0.5f * d * d : ad - 0.5f;
}

__global__ __launch_bounds__(1024) void rpn_finalize(
    const float* __restrict__ obj, const float4* __restrict__ props,
    const float4* __restrict__ gt,
    const u64* __restrict__ bufTopA,
    const u64* __restrict__ bufB, const u64* __restrict__ bufC,
    const u32* __restrict__ counters, float* __restrict__ out,
    u32 k2a, u32 k2b) {
  __shared__ u64 keyBuf[COMP_CAP];
  __shared__ u64 keyBuf2[1024];
  __shared__ u64 selKey[128];
  __shared__ u32 bestIdx[128];
  __shared__ u32 hist64[64];
  __shared__ float pr[16];
  __shared__ u32 s_cnt, s_cnt2, s_cutLo;
  __shared__ float s_reg, s_bcep;

  const u32 tid = threadIdx.x;
  const u32 lane = tid & 63u;
  const u32 wid = tid >> 6u;

  // ===== Phase 1: best_idx = top-128 of flat IoU (desc, ties idx asc) =====
  u32 nT = CSLOT(48); nT = nT < TOPA_CAP ? nT : TOPA_CAP;
  for (u32 i = tid; i < nT; i += 1024u) keyBuf[i] = bufTopA[i];
  __syncthreads();
  rank_select(keyBuf, nT, selKey);
  if (tid < 128u) {
    u64 k = selKey[tid];
    bestIdx[tid] = (k == 0ull) ? 0u : (0x1FFFFFFu - (u32)(k & 0x1FFFFFFu));
  }
  __syncthreads();

  // ===== Phase 2: positives = top-128 of [best_prio(128) ++ pos_prio] =====
  if (tid == 0u) { s_cnt = 128u; s_cnt2 = 0u; }
  if (tid < 64u) hist64[tid] = 0u;
  __syncthreads();
  if (tid < 128u) {
    u32 m2 = jax_bits32(k2a, k2b, tid) >> 9;
    keyBuf[tid] = ((u64)m2 << 25) | (u64)(0x1FFFFFFu - tid);
    if (m2 >= BCUT) atomicAdd(&hist64[(m2 - BCUT) >> 9], 1u);
  }
  for (u32 sdx = 0u; sdx < SHARDS; ++sdx) {
    u32 n = CSLOT(16u + sdx); n = n < SHARD_CAP ? n : SHARD_CAP;
    const u64* sb = bufB + (size_t)sdx * SHARD_CAP;
    for (u32 i = tid; i < n; i += 1024u) {
      u64 k = sb[i];
      u32 s = atomicAdd(&s_cnt, 1u);
      if (s < COMP_CAP) keyBuf[s] = k;
      atomicAdd(&hist64[((u32)(k >> 25) - BCUT) >> 9], 1u);
    }
  }
  __syncthreads();
  u32 nc = s_cnt < COMP_CAP ? s_cnt : COMP_CAP;
  if (wid == 0u) {  // single-wave 64-bin suffix cut, no barriers
    u32 suf = hist64[lane];
    for (u32 off = 1u; off < 64u; off <<= 1u) {
      u32 o = __shfl_down(suf, off, 64);
      if (lane + off < 64u) suf += o;
    }
    u64 ok = __ballot(suf >= 128u);
    u32 cutLo = 0u;
    if (ok) cutLo = BCUT + ((63u - (u32)__clzll(ok)) << 9);
    if (lane == 0u) s_cutLo = cutLo;
  }
  __syncthreads();
  {
    u64 cutKey = ((u64)s_cutLo) << 25;
    for (u32 i = tid; i < nc; i += 1024u) {
      u64 k = keyBuf[i];
      if (k >= cutKey) {
        u32 s = atomicAdd(&s_cnt2, 1u);
        if (s < 1024u) keyBuf2[s] = k;
      }
    }
  }
  __syncthreads();
  u32 ns = s_cnt2;
  if (ns <= 1024u) rank_select2(keyBuf2, ns, selKey);
  else rank_select(keyBuf, nc, selKey);

  float locReg = 0.0f, locBce = 0.0f;
  if (tid < 128u) {
    u64 k = selKey[tid];
    if (k != 0ull) {
      u32 c = 0x1FFFFFFu - (u32)(k & 0x1FFFFFFu);
      u32 pair = (c < 128u) ? bestIdx[c] : (c - 128u);
      if (pair < NM) {
        u32 row = pair / M_PROP, col = pair % M_PROP;
        float4 prb = props[col];
        float4 gb = gt[row];
        locReg = sl1(prb.x - gb.x) + sl1(prb.y - gb.y) +
                 sl1(prb.z - gb.z) + sl1(prb.w - gb.w);
        float l = obj[col];
        locBce = fmaxf(l, 0.0f) - l + log1pf(expf(-fabsf(l)));
      }
    }
  }
  {  // 2-barrier reductions via wave shfl (only waves 0-1 carry data)
    float v = locReg;
    for (u32 off = 32u; off > 0u; off >>= 1u) v += __shfl_xor(v, off, 64);
    if (lane == 0u) pr[wid] = v;
    __syncthreads();
    if (tid == 0u) {
      float s = 0.0f;
#pragma unroll
      for (u32 w = 0u; w < 16u; ++w) s += pr[w];
      s_reg = s;
    }
    __syncthreads();
    v = locBce;
    for (u32 off = 32u; off > 0u; off >>= 1u) v += __shfl_xor(v, off, 64);
    if (lane == 0u) pr[wid] = v;
    __syncthreads();
    if (tid == 0u) {
      float s = 0.0f;
#pragma unroll
      for (u32 w = 0u; w < 16u; ++w) s += pr[w];
      s_bcep = s;
    }
    __syncthreads();
  }

  // ===== Phase 3: negatives = top-128 of neg_prio =====
  if (tid == 0u) { s_cnt = 0u; s_cnt2 = 0u; }
  if (tid < 64u) hist64[tid] = 0u;
  __syncthreads();
  for (u32 sdx = 0u; sdx < SHARDS; ++sdx) {
    u32 n = CSLOT(sdx); n = n < SHARD_CAP ? n : SHARD_CAP;
    const u64* sb = bufC + (size_t)sdx * SHARD_CAP;
    for (u32 i = tid; i < n; i += 1024u) {
      u64 k = sb[i];
      u32 s = atomicAdd(&s_cnt, 1u);
      if (s < COMP_CAP) keyBuf[s] = k;
      atomicAdd(&hist64[((u32)(k >> 25) - CCUT) >> 4], 1u);
    }
  }
  __syncthreads();
  nc = s_cnt < COMP_CAP ? s_cnt : COMP_CAP;
  if (wid == 0u) {
    u32 suf = hist64[lane];
    for (u32 off = 1u; off < 64u; off <<= 1u) {
      u32 o = __shfl_down(suf, off, 64);
      if (lane + off < 64u) suf += o;
    }
    u64 ok = __ballot(suf >= 128u);
    u32 cutLo = 0u;
    if (ok) cutLo = CCUT + ((63u - (u32)__clzll(ok)) << 4);
    if (lane == 0u) s_cutLo = cutLo;
  }
  __syncthreads();
  {
    u64 cutKey = ((u64)s_cutLo) << 25;
    for (u32 i = tid; i < nc; i += 1024u) {
      u64 k = keyBuf[i];
      if (k >= cutKey) {
        u32 s = atomicAdd(&s_cnt2, 1u);
        if (s < 1024u) keyBuf2[s] = k;
      }
    }
  }
  __syncthreads();
  ns = s_cnt2;
  if (ns <= 1024u) rank_select2(keyBuf2, ns, selKey);
  else rank_select(keyBuf, nc, selKey);

  float locBceN = 0.0f;
  if (tid < 128u) {
    u64 k = selKey[tid];
    if (k != 0ull) {
      u32 idx = 0x1FFFFFFu - (u32)(k & 0x1FFFFFFu);
      u32 col = idx % M_PROP;
      float l = obj[col];
      locBceN = fmaxf(l, 0.0f) + log1pf(expf(-fabsf(l)));
    }
  }
  {
    float v = locBceN;
    for (u32 off = 32u; off > 0u; off >>= 1u) v += __shfl_xor(v, off, 64);
    if (lane == 0u) pr[wid] = v;
    __syncthreads();
    if (tid == 0u) {
      float s = 0.0f;
#pragma unroll
      for (u32 w = 0u; w < 16u; ++w) s += pr[w];
      float cls = (s_bcep + s) / 256.0f;
      float reg = s_reg / 512.0f;
      out[0] = cls + 10.0f * reg;
    }
  }
}

extern "C" void kernel_launch(void* const* d_in, const int* in_sizes, int n_in,
                              void* d_out, int out_size, void* d_ws, size_t ws_size,
                              hipStream_t stream) {
  (void)in_sizes; (void)n_in; (void)out_size; (void)ws_size;
  const float* obj = (const float*)d_in[0];
  const float4* props = (const float4*)d_in[1];
  const float4* gt = (const float4*)d_in[2];
  float* out = (float*)d_out;

  u32 k1a, k1b, k2a, k2b, k3a, k3b;
  jax_split3(k1a, k1b, k2a, k2b, k3a, k3b);

  // ws layout: counters(64KB padded slots) | gHistA(4KB) | bufTopA(64KB)
  //            | bufB(512KB) | bufC(512KB) | bufA(8MB)
  uint8_t* base = (uint8_t*)d_ws;
  u32* counters = (u32*)base;
  u32* gHistA = (u32*)(base + 65536);
  u64* bufTopA = (u64*)(base + 65536 + 4096);
  u64* bufB = (u64*)(base + 65536 + 4096 + (size_t)TOPA_CAP * 8);
  u64* bufC = bufB + (size_t)SHARDS * SHARD_CAP;
  u64* bufA = bufC + (size_t)SHARDS * SHARD_CAP;

  const u32 gridX = (M_PROP + 255u) / 256u;
  rpn_init<<<1, 256, 0, stream>>>(counters, gHistA);
  rpn_collect<<<dim3(gridX, GSPLIT), 256, 0, stream>>>(
      props, gt, bufA, bufB, bufC, counters, gHistA, k1a, k1b, k3a, k3b);
  rpn_filterA<<<64, 256, 0, stream>>>(bufA, gHistA, counters, bufTopA);
  rpn_finalize<<<1, 1024, 0, stream>>>(obj, props, gt, bufTopA, bufB, bufC,
                                       counters, out, k2a, k2b);
}